// Round 7
// baseline (327.640 us; speedup 1.0000x reference)
//
#include <hip/hip_runtime.h>
#include <math.h>

#define NN 10000
#define HEADS 8
#define NCLS 40
#define CHK 64
#define LOG2E 1.4426950408889634f

typedef __attribute__((ext_vector_type(8))) short short8;
typedef __attribute__((ext_vector_type(4))) float floatx4;

static __device__ __forceinline__ short f2bf(float f) {
    unsigned u = __builtin_bit_cast(unsigned, f);
    unsigned r = (u + 0x7fff + ((u >> 16) & 1)) >> 16;
    return (short)r;
}
static __device__ __forceinline__ float bf2f(unsigned short u) {
    unsigned x = ((unsigned)u) << 16;
    return __builtin_bit_cast(float, x);
}
static __device__ __forceinline__ void gl2lds16(const void* g, void* l) {
    __builtin_amdgcn_global_load_lds(
        (const __attribute__((address_space(1))) unsigned int*)g,
        (__attribute__((address_space(3))) unsigned int*)l, 16, 0, 0);
}

// ---------------- bf16 MFMA GEMM v3: BK=64, XOR-swizzled LDS, optional stats epilogue ----
__global__ __launch_bounds__(256) void gemm_bf16_v3(
    const short* __restrict__ A, const short* __restrict__ Bt,
    float* __restrict__ C, short* __restrict__ Cbf, const float* __restrict__ bias,
    float* __restrict__ stats, int M, int Nn, int K, float alpha)
{
    __shared__ short As[64 * 64];
    __shared__ short Bs[64 * 64];
    const int tid = threadIdx.x;
    const int w = tid >> 6, L = tid & 63;
    const int quad = L >> 4, lr = L & 15;
    const int col0 = blockIdx.x * 64, row0 = blockIdx.y * 64;

    const int srow = w * 16 + (L >> 3);
    const int schunk = (L & 7) ^ (L >> 3);
    int ga0 = row0 + srow;     if (ga0 > M - 1)  ga0 = M - 1;
    int ga1 = row0 + srow + 8; if (ga1 > M - 1)  ga1 = M - 1;
    int gb0 = col0 + srow;     if (gb0 > Nn - 1) gb0 = Nn - 1;
    int gb1 = col0 + srow + 8; if (gb1 > Nn - 1) gb1 = Nn - 1;
    const short* agp0 = A + (size_t)ga0 * K + schunk * 8;
    const short* agp1 = A + (size_t)ga1 * K + schunk * 8;
    const short* bgp0 = Bt + (size_t)gb0 * K + schunk * 8;
    const short* bgp1 = Bt + (size_t)gb1 * K + schunk * 8;
    short* alp0 = &As[w * 1024];
    short* alp1 = &As[w * 1024 + 512];
    short* blp0 = &Bs[w * 1024];
    short* blp1 = &Bs[w * 1024 + 512];

    floatx4 acc[4];
    const floatx4 zf = {0.f, 0.f, 0.f, 0.f};
    #pragma unroll
    for (int i = 0; i < 4; i++) acc[i] = zf;

    for (int k0 = 0; k0 < K; k0 += 64) {
        gl2lds16(agp0 + k0, alp0);
        gl2lds16(agp1 + k0, alp1);
        gl2lds16(bgp0 + k0, blp0);
        gl2lds16(bgp1 + k0, blp1);
        __syncthreads();
        #pragma unroll
        for (int ks = 0; ks < 2; ks++) {
            const int sl = ((ks * 4 + quad) ^ (lr & 7)) * 8;
            short8 bfr = *(const short8*)&Bs[(w * 16 + lr) * 64 + sl];
            #pragma unroll
            for (int i = 0; i < 4; i++) {
                short8 afr = *(const short8*)&As[(i * 16 + lr) * 64 + sl];
                acc[i] = __builtin_amdgcn_mfma_f32_16x16x32_bf16(afr, bfr, acc[i], 0, 0, 0);
            }
        }
        __syncthreads();
    }
    const int ccol = col0 + w * 16 + lr;
    float s = 0.f, s2 = 0.f;
    if (ccol < Nn) {
        float bv = bias ? bias[ccol] : 0.f;
        #pragma unroll
        for (int i = 0; i < 4; i++) {
            #pragma unroll
            for (int r = 0; r < 4; r++) {
                int crow = row0 + i * 16 + quad * 4 + r;
                if (crow < M) {
                    float v = alpha * acc[i][r] + bv;
                    if (C)   C[(size_t)crow * Nn + ccol] = v;
                    if (Cbf) Cbf[(size_t)crow * Nn + ccol] = f2bf(v);
                    s += v; s2 += v * v;
                }
            }
        }
    }
    if (stats) {
        s  += __shfl_xor(s, 16, 64);  s  += __shfl_xor(s, 32, 64);
        s2 += __shfl_xor(s2, 16, 64); s2 += __shfl_xor(s2, 32, 64);
        if (L < 16 && ccol < Nn) {
            atomicAdd(&stats[ccol], s);
            atomicAdd(&stats[256 + ccol], s2);
        }
    }
}

// ---------------- CSR build ----------------
__global__ void count_edges_kernel(const int* __restrict__ dst, int* counts, int E) {
    int e = blockIdx.x * 256 + threadIdx.x;
    if (e < E) atomicAdd(&counts[dst[e]], 1);
}

__global__ __launch_bounds__(1024) void scan_kernel(
    int* counts, int* offsets, int* cursor, int* elist, int n)
{
    const int P = (n + 1023) >> 10;
    __shared__ int wsum[16];
    int tid = threadIdx.x, lane = tid & 63, wid = tid >> 6;
    int base = tid * P;
    int local[16];
    int deg[16];
    int s = 0;
    for (int j = 0; j < P; j++) {
        int i = base + j;
        local[j] = s;
        deg[j] = (i < n) ? counts[i] + 1 : 0;   // +1 self-loop
        s += deg[j];
    }
    int inc = s;
    #pragma unroll
    for (int off = 1; off < 64; off <<= 1) {
        int tv = __shfl_up(inc, off, 64);
        if (lane >= off) inc += tv;
    }
    if (lane == 63) wsum[wid] = inc;
    __syncthreads();
    if (tid < 16) {
        int v = wsum[tid];
        int winc = v;
        #pragma unroll
        for (int off = 1; off < 16; off <<= 1) {
            int tv = __shfl_up(winc, off, 16);
            if (tid >= off) winc += tv;
        }
        wsum[tid] = winc - v;
    }
    __syncthreads();
    int excl = inc - s + wsum[wid];
    for (int j = 0; j < P; j++) {
        int i = base + j;
        if (i < n) {
            int o = excl + local[j];
            counts[i] = deg[j];
            offsets[i] = o;
            elist[o] = i;       // self-loop in slot 0
            cursor[i] = o + 1;
        }
    }
}

__global__ void scatter_edges_kernel(const int* __restrict__ src, const int* __restrict__ dst,
                                     int* cursor, int* elist, int E) {
    int e = blockIdx.x * 256 + threadIdx.x;
    if (e < E) {
        int d = dst[e];
        int pos = atomicAdd(&cursor[d], 1);
        elist[pos] = src[e];
    }
}

// ---------------- all weight/input prep in one launch ----------------
__global__ __launch_bounds__(256) void prep_all(
    const float* __restrict__ x, const float* __restrict__ W0,
    const float* __restrict__ W1, const float* __restrict__ a_src1,
    const float* __restrict__ a_dst1,
    short* __restrict__ xb, short* __restrict__ W0T, float* __restrict__ v1,
    short* __restrict__ W1pT)
{
    __shared__ float tile[32][33];
    const int b = blockIdx.x, t = threadIdx.x;
    if (b < 2500) {                 // cast x -> bf16 (x4 vectorized)
        int i = b * 256 + t;
        floatx4 v = ((const floatx4*)x)[i];
        short4 o = {f2bf(v[0]), f2bf(v[1]), f2bf(v[2]), f2bf(v[3])};
        ((short4*)xb)[i] = o;
    } else if (b < 2756) {          // W0T [256][256]
        int o = b - 2500;
        W0T[o * 256 + t] = f2bf(W0[t * 256 + o]);
    } else if (b < 2772) {          // v1 = folded W1·a  [256 f][16 j]
        int idx = (b - 2756) * 256 + t;
        int f = idx >> 4, j = idx & 15;
        int h = j & 7;
        const float* a = (j < 8) ? a_src1 : a_dst1;
        float s = 0.f;
        for (int c = 0; c < 256; c++)
            s += W1[f * 2048 + h * 256 + c] * a[h * 256 + c];
        v1[idx] = s;
    } else {                        // W1pT bf16 [256 c][2048 hf]
        int id = b - 2772;
        int h = id >> 6, f0 = ((id >> 3) & 7) * 32, c0 = (id & 7) * 32;
        int tx = t & 31, ty = t >> 5;
        for (int r = ty; r < 32; r += 8)
            tile[r][tx] = W1[(size_t)(f0 + r) * 2048 + h * 256 + c0 + tx];
        __syncthreads();
        for (int r = ty; r < 32; r += 8)
            W1pT[(size_t)(c0 + r) * 2048 + h * 256 + f0 + tx] = f2bf(tile[tx][r]);
    }
}

// ---------------- layer-0 node scores: wave per node ----------------
__global__ __launch_bounds__(256) void score0_wave(
    const unsigned short* __restrict__ h0b, const float* __restrict__ a_src,
    const float* __restrict__ a_dst, float* __restrict__ s0)
{
    const int wid = threadIdx.x >> 6, L = threadIdx.x & 63;
    const int n = blockIdx.x * 4 + wid;   // NN % 4 == 0: always valid
    ushort4 vv = *(const ushort4*)(h0b + (size_t)n * 256 + 4 * L);
    floatx4 as = *(const floatx4*)(a_src + 4 * L);
    floatx4 ad = *(const floatx4*)(a_dst + 4 * L);
    float v0 = bf2f(vv.x), v1_ = bf2f(vv.y), v2 = bf2f(vv.z), v3 = bf2f(vv.w);
    float ps = v0 * as[0] + v1_ * as[1] + v2 * as[2] + v3 * as[3];
    float pd = v0 * ad[0] + v1_ * ad[1] + v2 * ad[2] + v3 * ad[3];
    #pragma unroll
    for (int off = 1; off < 8; off <<= 1) {
        ps += __shfl_xor(ps, off, 64);
        pd += __shfl_xor(pd, off, 64);
    }
    if ((L & 7) == 0) {
        s0[n * 16 + (L >> 3)] = ps;
        s0[n * 16 + 8 + (L >> 3)] = pd;
    }
}

// ---------------- fused softmax(no-max)+aggregate+BN-stats, layer 0 ----------------
__global__ __launch_bounds__(256) void agg0_fused(
    const unsigned short* __restrict__ h0b, const float* __restrict__ s0,
    const int* __restrict__ offsets, const int* __restrict__ counts,
    const int* __restrict__ elist, float* __restrict__ out,
    float* __restrict__ stats)
{
    __shared__ float pw_s[4][CHK * 8];
    __shared__ int   sn_s[4][CHK];
    const int wid = threadIdx.x >> 6, L = threadIdx.x & 63;
    const int n = blockIdx.x * 4 + wid;   // NN % 4 == 0: always valid (barrier-safe)
    float* pw = pw_s[wid];
    int*   sw = sn_s[wid];
    const int deg = counts[n], start = offsets[n];
    const int hL = L >> 3;

    floatx4 sda = *(const floatx4*)(s0 + n * 16 + 8);
    floatx4 sdb = *(const floatx4*)(s0 + n * 16 + 12);
    float sd[8] = {sda[0], sda[1], sda[2], sda[3], sdb[0], sdb[1], sdb[2], sdb[3]};
    float lp[8] = {0.f, 0.f, 0.f, 0.f, 0.f, 0.f, 0.f, 0.f};
    float a0 = 0.f, a1 = 0.f, a2 = 0.f, a3 = 0.f;

    for (int e0 = 0; e0 < deg; e0 += CHK) {
        int ch = deg - e0; if (ch > CHK) ch = CHK;
        if (L < ch) {
            int sn = elist[start + e0 + L];
            sw[L] = sn;
            floatx4 ssa = *(const floatx4*)(s0 + sn * 16);
            floatx4 ssb = *(const floatx4*)(s0 + sn * 16 + 4);
            float ss[8] = {ssa[0], ssa[1], ssa[2], ssa[3], ssb[0], ssb[1], ssb[2], ssb[3]};
            float p[8];
            #pragma unroll
            for (int h = 0; h < 8; h++) {
                float v = ss[h] + sd[h];
                v = (v > 0.f) ? v : 0.2f * v;
                p[h] = exp2f(v * LOG2E);
                lp[h] += p[h];
            }
            floatx4 p0 = {p[0], p[1], p[2], p[3]};
            floatx4 p1 = {p[4], p[5], p[6], p[7]};
            *(floatx4*)&pw[L * 8] = p0;
            *(floatx4*)&pw[L * 8 + 4] = p1;
        }
        for (int e = 0; e < ch; e++) {
            float wgt = pw[e * 8 + hL];
            ushort4 vv = *(const ushort4*)(h0b + (size_t)sw[e] * 256 + 4 * L);
            a0 += wgt * bf2f(vv.x);
            a1 += wgt * bf2f(vv.y);
            a2 += wgt * bf2f(vv.z);
            a3 += wgt * bf2f(vv.w);
        }
    }
    #pragma unroll
    for (int off = 1; off < 64; off <<= 1)
        #pragma unroll
        for (int h = 0; h < 8; h++)
            lp[h] += __shfl_xor(lp[h], off, 64);
    float inv = 1.f / lp[hL];
    floatx4 o = {a0 * inv, a1 * inv, a2 * inv, a3 * inv};
    *(floatx4*)(out + (size_t)n * 256 + 4 * L) = o;

    // fused BN-stats: per-wave stash s/s2 in pw (done with it), cross-wave reduce, atomics
    floatx4 o2 = {o[0] * o[0], o[1] * o[1], o[2] * o[2], o[3] * o[3]};
    *(floatx4*)&pw[4 * L] = o;
    *(floatx4*)&pw[256 + 4 * L] = o2;
    __syncthreads();
    int c = threadIdx.x;   // 0..255 = column
    float sc_ = pw_s[0][c] + pw_s[1][c] + pw_s[2][c] + pw_s[3][c];
    float sc2 = pw_s[0][256 + c] + pw_s[1][256 + c] + pw_s[2][256 + c] + pw_s[3][256 + c];
    atomicAdd(&stats[c], sc_);
    atomicAdd(&stats[256 + c], sc2);
}

// ---------------- fused softmax(no-max)+aggregate, layer 1 (8 heads) ----------------
__global__ __launch_bounds__(256) void agg1_fused(
    const unsigned short* __restrict__ hb, const float* __restrict__ s1,
    const int* __restrict__ offsets, const int* __restrict__ counts,
    const int* __restrict__ elist, short* __restrict__ aggout)
{
    __shared__ float pw_s[4][CHK * 8];
    __shared__ int   sn_s[4][CHK];
    const int wid = threadIdx.x >> 6, L = threadIdx.x & 63;
    const int n = blockIdx.x * 4 + wid;   // NN % 4 == 0
    float* pw = pw_s[wid];
    int*   sw = sn_s[wid];
    const int deg = counts[n], start = offsets[n];

    floatx4 sda = *(const floatx4*)(s1 + n * 16 + 8);
    floatx4 sdb = *(const floatx4*)(s1 + n * 16 + 12);
    float sd[8] = {sda[0], sda[1], sda[2], sda[3], sdb[0], sdb[1], sdb[2], sdb[3]};
    float lp[8] = {0.f, 0.f, 0.f, 0.f, 0.f, 0.f, 0.f, 0.f};
    float acc[8][4];
    #pragma unroll
    for (int h = 0; h < 8; h++)
        #pragma unroll
        for (int f = 0; f < 4; f++) acc[h][f] = 0.f;

    for (int e0 = 0; e0 < deg; e0 += CHK) {
        int ch = deg - e0; if (ch > CHK) ch = CHK;
        if (L < ch) {
            int sn = elist[start + e0 + L];
            sw[L] = sn;
            floatx4 ssa = *(const floatx4*)(s1 + sn * 16);
            floatx4 ssb = *(const floatx4*)(s1 + sn * 16 + 4);
            float ss[8] = {ssa[0], ssa[1], ssa[2], ssa[3], ssb[0], ssb[1], ssb[2], ssb[3]};
            float p[8];
            #pragma unroll
            for (int h = 0; h < 8; h++) {
                float v = ss[h] + sd[h];
                v = (v > 0.f) ? v : 0.2f * v;
                p[h] = exp2f(v * LOG2E);
                lp[h] += p[h];
            }
            floatx4 p0 = {p[0], p[1], p[2], p[3]};
            floatx4 p1 = {p[4], p[5], p[6], p[7]};
            *(floatx4*)&pw[L * 8] = p0;
            *(floatx4*)&pw[L * 8 + 4] = p1;
        }
        for (int e = 0; e < ch; e++) {
            floatx4 pv0 = *(const floatx4*)&pw[e * 8];
            floatx4 pv1 = *(const floatx4*)&pw[e * 8 + 4];
            ushort4 vv = *(const ushort4*)(hb + (size_t)sw[e] * 256 + 4 * L);
            float v0 = bf2f(vv.x), v1_ = bf2f(vv.y), v2 = bf2f(vv.z), v3 = bf2f(vv.w);
            #pragma unroll
            for (int h = 0; h < 4; h++) {
                acc[h][0] += pv0[h] * v0;
                acc[h][1] += pv0[h] * v1_;
                acc[h][2] += pv0[h] * v2;
                acc[h][3] += pv0[h] * v3;
                acc[h + 4][0] += pv1[h] * v0;
                acc[h + 4][1] += pv1[h] * v1_;
                acc[h + 4][2] += pv1[h] * v2;
                acc[h + 4][3] += pv1[h] * v3;
            }
        }
    }
    #pragma unroll
    for (int off = 1; off < 64; off <<= 1)
        #pragma unroll
        for (int h = 0; h < 8; h++)
            lp[h] += __shfl_xor(lp[h], off, 64);
    #pragma unroll
    for (int h = 0; h < 8; h++) {
        float inv = 1.f / lp[h];
        short4 o = {f2bf(acc[h][0] * inv), f2bf(acc[h][1] * inv),
                    f2bf(acc[h][2] * inv), f2bf(acc[h][3] * inv)};
        *(short4*)(aggout + (size_t)n * 2048 + h * 256 + 4 * L) = o;
    }
}

// ---------------- BN + ELU + bf16 write + layer-1 score, one block per node ----------------
__global__ __launch_bounds__(256) void bnapply_score1(
    const float* __restrict__ xg, const float* __restrict__ stats,
    const float* __restrict__ g, const float* __restrict__ be,
    const float* __restrict__ v1, short* __restrict__ hactb, float* __restrict__ s1)
{
    __shared__ float row[256];
    __shared__ float part[16][17];
    const int n = blockIdx.x, t = threadIdx.x;
    const float invN = 1.0f / NN;
    float mu = stats[t] * invN;
    float var = stats[256 + t] * invN - mu * mu;
    float v = g[t] * (xg[(size_t)n * 256 + t] - mu) * rsqrtf(var + 1e-5f) + be[t];
    v = (v > 0.f) ? v : (expf(v) - 1.f);   // ELU
    hactb[(size_t)n * 256 + t] = f2bf(v);
    row[t] = v;
    __syncthreads();
    int j = t & 15, f0 = t >> 4;
    float p = 0.f;
    #pragma unroll
    for (int k = 0; k < 16; k++)
        p += row[f0 * 16 + k] * v1[(f0 * 16 + k) * 16 + j];
    part[f0][j] = p;
    __syncthreads();
    if (t < 16) {
        float s = 0.f;
        #pragma unroll
        for (int k = 0; k < 16; k++) s += part[k][t];
        s1[n * 16 + t] = s;
    }
}

// ---------------- BN + ELU + residual + 40-col classifier matvec, block per node ----------
__global__ __launch_bounds__(256) void bnapply_cls(
    const float* __restrict__ out1, const float* __restrict__ stats,
    const float* __restrict__ g, const float* __restrict__ be,
    const unsigned short* __restrict__ hactb, const float* __restrict__ Wc,
    const float* __restrict__ bc, float* __restrict__ out)
{
    __shared__ float row[256];
    __shared__ float part[16][17];
    const int n = blockIdx.x, t = threadIdx.x;
    const float invN = 1.0f / NN;
    float mu = stats[t] * invN;
    float var = stats[256 + t] * invN - mu * mu;
    float v = g[t] * (out1[(size_t)n * 256 + t] - mu) * rsqrtf(var + 1e-5f) + be[t];
    v = (v > 0.f) ? v : (expf(v) - 1.f);   // ELU
    v += bf2f(hactb[(size_t)n * 256 + t]); // residual (h_in)
    row[t] = v;
    __syncthreads();
    const int j16 = t & 15, f0 = t >> 4;
    #pragma unroll
    for (int grp = 0; grp < 3; grp++) {
        int col = grp * 16 + j16;
        float p = 0.f;
        if (col < NCLS) {
            #pragma unroll
            for (int k = 0; k < 16; k++)
                p += row[f0 * 16 + k] * Wc[(f0 * 16 + k) * NCLS + col];
        }
        part[f0][j16] = p;
        __syncthreads();
        if (t < 16) {
            int c = grp * 16 + t;
            if (c < NCLS) {
                float s = 0.f;
                #pragma unroll
                for (int k = 0; k < 16; k++) s += part[k][t];
                out[(size_t)n * NCLS + c] = s + bc[c];
            }
        }
        __syncthreads();
    }
}

// ---------------- launch ----------------
extern "C" void kernel_launch(void* const* d_in, const int* in_sizes, int n_in,
                              void* d_out, int out_size, void* d_ws, size_t ws_size,
                              hipStream_t stream) {
    const float* x      = (const float*)d_in[0];
    const int*   eidx   = (const int*)d_in[1];
    const float* W0     = (const float*)d_in[2];
    const float* a_src0 = (const float*)d_in[3];
    const float* a_dst0 = (const float*)d_in[4];
    const float* g0     = (const float*)d_in[6];
    const float* be0    = (const float*)d_in[7];
    const float* W1     = (const float*)d_in[8];
    const float* a_src1 = (const float*)d_in[9];
    const float* a_dst1 = (const float*)d_in[10];
    const float* g1     = (const float*)d_in[12];
    const float* be1    = (const float*)d_in[13];
    const float* Wc     = (const float*)d_in[14];
    const float* bc     = (const float*)d_in[15];
    float* out = (float*)d_out;

    const int E = in_sizes[1] / 2;
    const int* esrc = eidx;
    const int* edst = eidx + E;

    char* ws = (char*)d_ws;
    size_t off = 0;
    auto alloc = [&](size_t bytes) {
        void* p = ws + off;
        off += (bytes + 255) & ~(size_t)255;
        return p;
    };
    // stats + counts contiguous -> single memset
    float* stats   = (float*)alloc(1024 * 4);
    int*   counts  = (int*)alloc(NN * 4);
    float* out1    = (float*)alloc((size_t)NN * 256 * 4);
    short* h0b     = (short*)alloc((size_t)NN * 256 * 2);
    short* xb      = (short*)alloc((size_t)NN * 256 * 2);
    float* s0      = (float*)alloc((size_t)NN * 16 * 4);
    float* s1      = (float*)alloc((size_t)NN * 16 * 4);
    float* v1      = (float*)alloc(4096 * 4);
    float* h_gat0  = (float*)alloc((size_t)NN * 256 * 4);
    short* hactb   = (short*)alloc((size_t)NN * 256 * 2);
    short* agg1bf  = (short*)alloc((size_t)NN * 2048 * 2);
    short* W0T     = (short*)alloc((size_t)256 * 256 * 2);
    short* W1pT    = (short*)alloc((size_t)256 * 2048 * 2);
    int* offsets   = (int*)alloc((NN + 16) * 4);
    int* cursor    = (int*)alloc(NN * 4);
    int* elist     = (int*)alloc((size_t)(E + NN) * 4);

    float* stats0 = stats;
    float* stats1 = stats + 512;

    hipMemsetAsync(stats, 0, 1024 * 4 + NN * 4, stream);   // stats0+stats1+counts

    // CSR build
    count_edges_kernel<<<(E + 255) / 256, 256, 0, stream>>>(edst, counts, E);
    scan_kernel<<<1, 1024, 0, stream>>>(counts, offsets, cursor, elist, NN);
    scatter_edges_kernel<<<(E + 255) / 256, 256, 0, stream>>>(esrc, edst, cursor, elist, E);

    // all prep in one launch (2500 + 256 + 16 + 512 blocks)
    prep_all<<<3284, 256, 0, stream>>>(x, W0, W1, a_src1, a_dst1,
                                       xb, W0T, v1, W1pT);

    // layer 0
    {
        dim3 grid(4, (NN + 63) / 64);
        gemm_bf16_v3<<<grid, 256, 0, stream>>>(xb, W0T, nullptr, h0b, nullptr, nullptr,
                                               NN, 256, 256, 1.0f);
    }
    score0_wave<<<NN / 4, 256, 0, stream>>>(
        (const unsigned short*)h0b, a_src0, a_dst0, s0);
    agg0_fused<<<NN / 4, 256, 0, stream>>>(
        (const unsigned short*)h0b, s0, offsets, counts, elist, h_gat0, stats0);
    bnapply_score1<<<NN, 256, 0, stream>>>(h_gat0, stats0, g0, be0, v1, hactb, s1);

    // layer 1
    agg1_fused<<<NN / 4, 256, 0, stream>>>(
        (const unsigned short*)hactb, s1, offsets, counts, elist, agg1bf);
    {
        dim3 grid(4, (NN + 63) / 64);
        gemm_bf16_v3<<<grid, 256, 0, stream>>>(agg1bf, W1pT, out1, nullptr, nullptr, stats1,
                                               NN, 256, 2048, 0.125f);
    }

    // BN + ELU + residual + classifier, fused
    bnapply_cls<<<NN, 256, 0, stream>>>(out1, stats1, g1, be1,
                                        (const unsigned short*)hactb, Wc, bc, out);
}

// Round 8
// 290.873 us; speedup vs baseline: 1.1264x; 1.1264x over previous
//
#include <hip/hip_runtime.h>
#include <math.h>

#define NN 10000
#define HEADS 8
#define NCLS 40
#define CHK 64
#define LOG2E 1.4426950408889634f

typedef __attribute__((ext_vector_type(8))) short short8;
typedef __attribute__((ext_vector_type(4))) float floatx4;

static __device__ __forceinline__ short f2bf(float f) {
    unsigned u = __builtin_bit_cast(unsigned, f);
    unsigned r = (u + 0x7fff + ((u >> 16) & 1)) >> 16;
    return (short)r;
}
static __device__ __forceinline__ float bf2f(unsigned short u) {
    unsigned x = ((unsigned)u) << 16;
    return __builtin_bit_cast(float, x);
}
static __device__ __forceinline__ void gl2lds16(const void* g, void* l) {
    __builtin_amdgcn_global_load_lds(
        (const __attribute__((address_space(1))) unsigned int*)g,
        (__attribute__((address_space(3))) unsigned int*)l, 16, 0, 0);
}

// ---------------- bf16 MFMA GEMM v3: BK=64, XOR-swizzled LDS, optional stats epilogue ----
__global__ __launch_bounds__(256) void gemm_bf16_v3(
    const short* __restrict__ A, const short* __restrict__ Bt,
    float* __restrict__ C, short* __restrict__ Cbf, const float* __restrict__ bias,
    float* __restrict__ stats, int M, int Nn, int K, float alpha)
{
    __shared__ short As[64 * 64];
    __shared__ short Bs[64 * 64];
    const int tid = threadIdx.x;
    const int w = tid >> 6, L = tid & 63;
    const int quad = L >> 4, lr = L & 15;
    const int col0 = blockIdx.x * 64, row0 = blockIdx.y * 64;

    const int srow = w * 16 + (L >> 3);
    const int schunk = (L & 7) ^ (L >> 3);
    int ga0 = row0 + srow;     if (ga0 > M - 1)  ga0 = M - 1;
    int ga1 = row0 + srow + 8; if (ga1 > M - 1)  ga1 = M - 1;
    int gb0 = col0 + srow;     if (gb0 > Nn - 1) gb0 = Nn - 1;
    int gb1 = col0 + srow + 8; if (gb1 > Nn - 1) gb1 = Nn - 1;
    const short* agp0 = A + (size_t)ga0 * K + schunk * 8;
    const short* agp1 = A + (size_t)ga1 * K + schunk * 8;
    const short* bgp0 = Bt + (size_t)gb0 * K + schunk * 8;
    const short* bgp1 = Bt + (size_t)gb1 * K + schunk * 8;
    short* alp0 = &As[w * 1024];
    short* alp1 = &As[w * 1024 + 512];
    short* blp0 = &Bs[w * 1024];
    short* blp1 = &Bs[w * 1024 + 512];

    floatx4 acc[4];
    const floatx4 zf = {0.f, 0.f, 0.f, 0.f};
    #pragma unroll
    for (int i = 0; i < 4; i++) acc[i] = zf;

    for (int k0 = 0; k0 < K; k0 += 64) {
        gl2lds16(agp0 + k0, alp0);
        gl2lds16(agp1 + k0, alp1);
        gl2lds16(bgp0 + k0, blp0);
        gl2lds16(bgp1 + k0, blp1);
        __syncthreads();
        #pragma unroll
        for (int ks = 0; ks < 2; ks++) {
            const int sl = ((ks * 4 + quad) ^ (lr & 7)) * 8;
            short8 bfr = *(const short8*)&Bs[(w * 16 + lr) * 64 + sl];
            #pragma unroll
            for (int i = 0; i < 4; i++) {
                short8 afr = *(const short8*)&As[(i * 16 + lr) * 64 + sl];
                acc[i] = __builtin_amdgcn_mfma_f32_16x16x32_bf16(afr, bfr, acc[i], 0, 0, 0);
            }
        }
        __syncthreads();
    }
    const int ccol = col0 + w * 16 + lr;
    float s = 0.f, s2 = 0.f;
    if (ccol < Nn) {
        float bv = bias ? bias[ccol] : 0.f;
        #pragma unroll
        for (int i = 0; i < 4; i++) {
            #pragma unroll
            for (int r = 0; r < 4; r++) {
                int crow = row0 + i * 16 + quad * 4 + r;
                if (crow < M) {
                    float v = alpha * acc[i][r] + bv;
                    if (C)   C[(size_t)crow * Nn + ccol] = v;
                    if (Cbf) Cbf[(size_t)crow * Nn + ccol] = f2bf(v);
                    s += v; s2 += v * v;
                }
            }
        }
    }
    if (stats) {   // 157 blocks only -> acceptable contention
        s  += __shfl_xor(s, 16, 64);  s  += __shfl_xor(s, 32, 64);
        s2 += __shfl_xor(s2, 16, 64); s2 += __shfl_xor(s2, 32, 64);
        if (L < 16 && ccol < Nn) {
            atomicAdd(&stats[ccol], s);
            atomicAdd(&stats[256 + ccol], s2);
        }
    }
}

// ---------------- CSR build ----------------
__global__ void count_edges_kernel(const int* __restrict__ dst, int* counts, int E) {
    int e = blockIdx.x * 256 + threadIdx.x;
    if (e < E) atomicAdd(&counts[dst[e]], 1);
}

__global__ __launch_bounds__(1024) void scan_kernel(
    int* counts, int* offsets, int* cursor, int* elist, int n)
{
    const int P = (n + 1023) >> 10;
    __shared__ int wsum[16];
    int tid = threadIdx.x, lane = tid & 63, wid = tid >> 6;
    int base = tid * P;
    int local[16];
    int deg[16];
    int s = 0;
    for (int j = 0; j < P; j++) {
        int i = base + j;
        local[j] = s;
        deg[j] = (i < n) ? counts[i] + 1 : 0;   // +1 self-loop
        s += deg[j];
    }
    int inc = s;
    #pragma unroll
    for (int off = 1; off < 64; off <<= 1) {
        int tv = __shfl_up(inc, off, 64);
        if (lane >= off) inc += tv;
    }
    if (lane == 63) wsum[wid] = inc;
    __syncthreads();
    if (tid < 16) {
        int v = wsum[tid];
        int winc = v;
        #pragma unroll
        for (int off = 1; off < 16; off <<= 1) {
            int tv = __shfl_up(winc, off, 16);
            if (tid >= off) winc += tv;
        }
        wsum[tid] = winc - v;
    }
    __syncthreads();
    int excl = inc - s + wsum[wid];
    for (int j = 0; j < P; j++) {
        int i = base + j;
        if (i < n) {
            int o = excl + local[j];
            counts[i] = deg[j];
            offsets[i] = o;
            elist[o] = i;       // self-loop in slot 0
            cursor[i] = o + 1;
        }
    }
}

__global__ void scatter_edges_kernel(const int* __restrict__ src, const int* __restrict__ dst,
                                     int* cursor, int* elist, int E) {
    int e = blockIdx.x * 256 + threadIdx.x;
    if (e < E) {
        int d = dst[e];
        int pos = atomicAdd(&cursor[d], 1);
        elist[pos] = src[e];
    }
}

// ---------------- all weight/input prep in one launch ----------------
__global__ __launch_bounds__(256) void prep_all(
    const float* __restrict__ x, const float* __restrict__ W0,
    const float* __restrict__ W1, const float* __restrict__ a_src1,
    const float* __restrict__ a_dst1,
    short* __restrict__ xb, short* __restrict__ W0T, float* __restrict__ v1,
    short* __restrict__ W1pT)
{
    __shared__ float tile[32][33];
    const int b = blockIdx.x, t = threadIdx.x;
    if (b < 2500) {                 // cast x -> bf16 (x4 vectorized)
        int i = b * 256 + t;
        floatx4 v = ((const floatx4*)x)[i];
        short4 o = {f2bf(v[0]), f2bf(v[1]), f2bf(v[2]), f2bf(v[3])};
        ((short4*)xb)[i] = o;
    } else if (b < 2756) {          // W0T [256][256]
        int o = b - 2500;
        W0T[o * 256 + t] = f2bf(W0[t * 256 + o]);
    } else if (b < 2772) {          // v1 = folded W1·a  [256 f][16 j]
        int idx = (b - 2756) * 256 + t;
        int f = idx >> 4, j = idx & 15;
        int h = j & 7;
        const float* a = (j < 8) ? a_src1 : a_dst1;
        float s = 0.f;
        for (int c = 0; c < 256; c++)
            s += W1[f * 2048 + h * 256 + c] * a[h * 256 + c];
        v1[idx] = s;
    } else {                        // W1pT bf16 [256 c][2048 hf]
        int id = b - 2772;
        int h = id >> 6, f0 = ((id >> 3) & 7) * 32, c0 = (id & 7) * 32;
        int tx = t & 31, ty = t >> 5;
        for (int r = ty; r < 32; r += 8)
            tile[r][tx] = W1[(size_t)(f0 + r) * 2048 + h * 256 + c0 + tx];
        __syncthreads();
        for (int r = ty; r < 32; r += 8)
            W1pT[(size_t)(c0 + r) * 2048 + h * 256 + f0 + tx] = f2bf(tile[tx][r]);
    }
}

// ---------------- layer-0 node scores: wave per node ----------------
__global__ __launch_bounds__(256) void score0_wave(
    const unsigned short* __restrict__ h0b, const float* __restrict__ a_src,
    const float* __restrict__ a_dst, float* __restrict__ s0)
{
    const int wid = threadIdx.x >> 6, L = threadIdx.x & 63;
    const int n = blockIdx.x * 4 + wid;   // NN % 4 == 0: always valid
    ushort4 vv = *(const ushort4*)(h0b + (size_t)n * 256 + 4 * L);
    floatx4 as = *(const floatx4*)(a_src + 4 * L);
    floatx4 ad = *(const floatx4*)(a_dst + 4 * L);
    float v0 = bf2f(vv.x), v1_ = bf2f(vv.y), v2 = bf2f(vv.z), v3 = bf2f(vv.w);
    float ps = v0 * as[0] + v1_ * as[1] + v2 * as[2] + v3 * as[3];
    float pd = v0 * ad[0] + v1_ * ad[1] + v2 * ad[2] + v3 * ad[3];
    #pragma unroll
    for (int off = 1; off < 8; off <<= 1) {
        ps += __shfl_xor(ps, off, 64);
        pd += __shfl_xor(pd, off, 64);
    }
    if ((L & 7) == 0) {
        s0[n * 16 + (L >> 3)] = ps;
        s0[n * 16 + 8 + (L >> 3)] = pd;
    }
}

// ---------------- fused softmax(no-max)+aggregate, layer 0 (barrier-free) ----------------
__global__ __launch_bounds__(256) void agg0_fused(
    const unsigned short* __restrict__ h0b, const float* __restrict__ s0,
    const int* __restrict__ offsets, const int* __restrict__ counts,
    const int* __restrict__ elist, float* __restrict__ out)
{
    __shared__ float pw_s[4][CHK * 8];
    __shared__ int   sn_s[4][CHK];
    const int wid = threadIdx.x >> 6, L = threadIdx.x & 63;
    const int n = blockIdx.x * 4 + wid;   // NN % 4 == 0
    float* pw = pw_s[wid];
    int*   sw = sn_s[wid];
    const int deg = counts[n], start = offsets[n];
    const int hL = L >> 3;

    floatx4 sda = *(const floatx4*)(s0 + n * 16 + 8);
    floatx4 sdb = *(const floatx4*)(s0 + n * 16 + 12);
    float sd[8] = {sda[0], sda[1], sda[2], sda[3], sdb[0], sdb[1], sdb[2], sdb[3]};
    float lp[8] = {0.f, 0.f, 0.f, 0.f, 0.f, 0.f, 0.f, 0.f};
    float a0 = 0.f, a1 = 0.f, a2 = 0.f, a3 = 0.f;

    for (int e0 = 0; e0 < deg; e0 += CHK) {
        int ch = deg - e0; if (ch > CHK) ch = CHK;
        if (L < ch) {
            int sn = elist[start + e0 + L];
            sw[L] = sn;
            floatx4 ssa = *(const floatx4*)(s0 + sn * 16);
            floatx4 ssb = *(const floatx4*)(s0 + sn * 16 + 4);
            float ss[8] = {ssa[0], ssa[1], ssa[2], ssa[3], ssb[0], ssb[1], ssb[2], ssb[3]};
            float p[8];
            #pragma unroll
            for (int h = 0; h < 8; h++) {
                float v = ss[h] + sd[h];
                v = (v > 0.f) ? v : 0.2f * v;
                p[h] = exp2f(v * LOG2E);
                lp[h] += p[h];
            }
            floatx4 p0 = {p[0], p[1], p[2], p[3]};
            floatx4 p1 = {p[4], p[5], p[6], p[7]};
            *(floatx4*)&pw[L * 8] = p0;
            *(floatx4*)&pw[L * 8 + 4] = p1;
        }
        for (int e = 0; e < ch; e++) {
            float wgt = pw[e * 8 + hL];
            ushort4 vv = *(const ushort4*)(h0b + (size_t)sw[e] * 256 + 4 * L);
            a0 += wgt * bf2f(vv.x);
            a1 += wgt * bf2f(vv.y);
            a2 += wgt * bf2f(vv.z);
            a3 += wgt * bf2f(vv.w);
        }
    }
    #pragma unroll
    for (int off = 1; off < 64; off <<= 1)
        #pragma unroll
        for (int h = 0; h < 8; h++)
            lp[h] += __shfl_xor(lp[h], off, 64);
    float inv = 1.f / lp[hL];
    floatx4 o = {a0 * inv, a1 * inv, a2 * inv, a3 * inv};
    *(floatx4*)(out + (size_t)n * 256 + 4 * L) = o;
}

// ---------------- fused softmax(no-max)+aggregate, layer 1 (8 heads) ----------------
__global__ __launch_bounds__(256) void agg1_fused(
    const unsigned short* __restrict__ hb, const float* __restrict__ s1,
    const int* __restrict__ offsets, const int* __restrict__ counts,
    const int* __restrict__ elist, short* __restrict__ aggout)
{
    __shared__ float pw_s[4][CHK * 8];
    __shared__ int   sn_s[4][CHK];
    const int wid = threadIdx.x >> 6, L = threadIdx.x & 63;
    const int n = blockIdx.x * 4 + wid;   // NN % 4 == 0
    float* pw = pw_s[wid];
    int*   sw = sn_s[wid];
    const int deg = counts[n], start = offsets[n];

    floatx4 sda = *(const floatx4*)(s1 + n * 16 + 8);
    floatx4 sdb = *(const floatx4*)(s1 + n * 16 + 12);
    float sd[8] = {sda[0], sda[1], sda[2], sda[3], sdb[0], sdb[1], sdb[2], sdb[3]};
    float lp[8] = {0.f, 0.f, 0.f, 0.f, 0.f, 0.f, 0.f, 0.f};
    float acc[8][4];
    #pragma unroll
    for (int h = 0; h < 8; h++)
        #pragma unroll
        for (int f = 0; f < 4; f++) acc[h][f] = 0.f;

    for (int e0 = 0; e0 < deg; e0 += CHK) {
        int ch = deg - e0; if (ch > CHK) ch = CHK;
        if (L < ch) {
            int sn = elist[start + e0 + L];
            sw[L] = sn;
            floatx4 ssa = *(const floatx4*)(s1 + sn * 16);
            floatx4 ssb = *(const floatx4*)(s1 + sn * 16 + 4);
            float ss[8] = {ssa[0], ssa[1], ssa[2], ssa[3], ssb[0], ssb[1], ssb[2], ssb[3]};
            float p[8];
            #pragma unroll
            for (int h = 0; h < 8; h++) {
                float v = ss[h] + sd[h];
                v = (v > 0.f) ? v : 0.2f * v;
                p[h] = exp2f(v * LOG2E);
                lp[h] += p[h];
            }
            floatx4 p0 = {p[0], p[1], p[2], p[3]};
            floatx4 p1 = {p[4], p[5], p[6], p[7]};
            *(floatx4*)&pw[L * 8] = p0;
            *(floatx4*)&pw[L * 8 + 4] = p1;
        }
        for (int e = 0; e < ch; e++) {
            floatx4 pv0 = *(const floatx4*)&pw[e * 8];
            floatx4 pv1 = *(const floatx4*)&pw[e * 8 + 4];
            ushort4 vv = *(const ushort4*)(hb + (size_t)sw[e] * 256 + 4 * L);
            float v0 = bf2f(vv.x), v1_ = bf2f(vv.y), v2 = bf2f(vv.z), v3 = bf2f(vv.w);
            #pragma unroll
            for (int h = 0; h < 4; h++) {
                acc[h][0] += pv0[h] * v0;
                acc[h][1] += pv0[h] * v1_;
                acc[h][2] += pv0[h] * v2;
                acc[h][3] += pv0[h] * v3;
                acc[h + 4][0] += pv1[h] * v0;
                acc[h + 4][1] += pv1[h] * v1_;
                acc[h + 4][2] += pv1[h] * v2;
                acc[h + 4][3] += pv1[h] * v3;
            }
        }
    }
    #pragma unroll
    for (int off = 1; off < 64; off <<= 1)
        #pragma unroll
        for (int h = 0; h < 8; h++)
            lp[h] += __shfl_xor(lp[h], off, 64);
    #pragma unroll
    for (int h = 0; h < 8; h++) {
        float inv = 1.f / lp[h];
        short4 o = {f2bf(acc[h][0] * inv), f2bf(acc[h][1] * inv),
                    f2bf(acc[h][2] * inv), f2bf(acc[h][3] * inv)};
        *(short4*)(aggout + (size_t)n * 2048 + h * 256 + 4 * L) = o;
    }
}

// ---------------- batchnorm stats (256 blocks -> low atomic contention) ----------------
__global__ __launch_bounds__(256) void bn_stats_kernel(const float* __restrict__ x, float* stats, int n) {
    int t = threadIdx.x;
    float s = 0.f, s2 = 0.f;
    for (int r = blockIdx.x; r < n; r += gridDim.x) {
        float v = x[(size_t)r * 256 + t];
        s += v; s2 += v * v;
    }
    atomicAdd(&stats[t], s);
    atomicAdd(&stats[256 + t], s2);
}

// ---------------- BN + ELU + bf16 write + layer-1 score, one block per node ----------------
__global__ __launch_bounds__(256) void bnapply_score1(
    const float* __restrict__ xg, const float* __restrict__ stats,
    const float* __restrict__ g, const float* __restrict__ be,
    const float* __restrict__ v1, short* __restrict__ hactb, float* __restrict__ s1)
{
    __shared__ float row[256];
    __shared__ float part[16][17];
    const int n = blockIdx.x, t = threadIdx.x;
    const float invN = 1.0f / NN;
    float mu = stats[t] * invN;
    float var = stats[256 + t] * invN - mu * mu;
    float v = g[t] * (xg[(size_t)n * 256 + t] - mu) * rsqrtf(var + 1e-5f) + be[t];
    v = (v > 0.f) ? v : (expf(v) - 1.f);   // ELU
    hactb[(size_t)n * 256 + t] = f2bf(v);
    row[t] = v;
    __syncthreads();
    int j = t & 15, f0 = t >> 4;
    float p = 0.f;
    #pragma unroll
    for (int k = 0; k < 16; k++)
        p += row[f0 * 16 + k] * v1[(f0 * 16 + k) * 16 + j];
    part[f0][j] = p;
    __syncthreads();
    if (t < 16) {
        float s = 0.f;
        #pragma unroll
        for (int k = 0; k < 16; k++) s += part[k][t];
        s1[n * 16 + t] = s;
    }
}

// ---------------- BN + ELU + residual + 40-col classifier matvec, block per node ----------
__global__ __launch_bounds__(256) void bnapply_cls(
    const float* __restrict__ out1, const float* __restrict__ stats,
    const float* __restrict__ g, const float* __restrict__ be,
    const unsigned short* __restrict__ hactb, const float* __restrict__ Wc,
    const float* __restrict__ bc, float* __restrict__ out)
{
    __shared__ float row[256];
    __shared__ float part[16][17];
    const int n = blockIdx.x, t = threadIdx.x;
    const float invN = 1.0f / NN;
    float mu = stats[t] * invN;
    float var = stats[256 + t] * invN - mu * mu;
    float v = g[t] * (out1[(size_t)n * 256 + t] - mu) * rsqrtf(var + 1e-5f) + be[t];
    v = (v > 0.f) ? v : (expf(v) - 1.f);   // ELU
    v += bf2f(hactb[(size_t)n * 256 + t]); // residual (h_in)
    row[t] = v;
    __syncthreads();
    const int j16 = t & 15, f0 = t >> 4;
    #pragma unroll
    for (int grp = 0; grp < 3; grp++) {
        int col = grp * 16 + j16;
        float p = 0.f;
        if (col < NCLS) {
            #pragma unroll
            for (int k = 0; k < 16; k++)
                p += row[f0 * 16 + k] * Wc[(f0 * 16 + k) * NCLS + col];
        }
        part[f0][j16] = p;
        __syncthreads();
        if (t < 16) {
            int c = grp * 16 + t;
            if (c < NCLS) {
                float s = 0.f;
                #pragma unroll
                for (int k = 0; k < 16; k++) s += part[k][t];
                out[(size_t)n * NCLS + c] = s + bc[c];
            }
        }
        __syncthreads();
    }
}

// ---------------- launch ----------------
extern "C" void kernel_launch(void* const* d_in, const int* in_sizes, int n_in,
                              void* d_out, int out_size, void* d_ws, size_t ws_size,
                              hipStream_t stream) {
    const float* x      = (const float*)d_in[0];
    const int*   eidx   = (const int*)d_in[1];
    const float* W0     = (const float*)d_in[2];
    const float* a_src0 = (const float*)d_in[3];
    const float* a_dst0 = (const float*)d_in[4];
    const float* g0     = (const float*)d_in[6];
    const float* be0    = (const float*)d_in[7];
    const float* W1     = (const float*)d_in[8];
    const float* a_src1 = (const float*)d_in[9];
    const float* a_dst1 = (const float*)d_in[10];
    const float* g1     = (const float*)d_in[12];
    const float* be1    = (const float*)d_in[13];
    const float* Wc     = (const float*)d_in[14];
    const float* bc     = (const float*)d_in[15];
    float* out = (float*)d_out;

    const int E = in_sizes[1] / 2;
    const int* esrc = eidx;
    const int* edst = eidx + E;

    char* ws = (char*)d_ws;
    size_t off = 0;
    auto alloc = [&](size_t bytes) {
        void* p = ws + off;
        off += (bytes + 255) & ~(size_t)255;
        return p;
    };
    // stats + counts contiguous -> single memset
    float* stats   = (float*)alloc(1024 * 4);
    int*   counts  = (int*)alloc(NN * 4);
    float* out1    = (float*)alloc((size_t)NN * 256 * 4);
    short* h0b     = (short*)alloc((size_t)NN * 256 * 2);
    short* xb      = (short*)alloc((size_t)NN * 256 * 2);
    float* s0      = (float*)alloc((size_t)NN * 16 * 4);
    float* s1      = (float*)alloc((size_t)NN * 16 * 4);
    float* v1      = (float*)alloc(4096 * 4);
    float* h_gat0  = (float*)alloc((size_t)NN * 256 * 4);
    short* hactb   = (short*)alloc((size_t)NN * 256 * 2);
    short* agg1bf  = (short*)alloc((size_t)NN * 2048 * 2);
    short* W0T     = (short*)alloc((size_t)256 * 256 * 2);
    short* W1pT    = (short*)alloc((size_t)256 * 2048 * 2);
    int* offsets   = (int*)alloc((NN + 16) * 4);
    int* cursor    = (int*)alloc(NN * 4);
    int* elist     = (int*)alloc((size_t)(E + NN) * 4);

    float* stats0 = stats;
    float* stats1 = stats + 512;

    hipMemsetAsync(stats, 0, 1024 * 4 + NN * 4, stream);   // stats0+stats1+counts

    // CSR build
    count_edges_kernel<<<(E + 255) / 256, 256, 0, stream>>>(edst, counts, E);
    scan_kernel<<<1, 1024, 0, stream>>>(counts, offsets, cursor, elist, NN);
    scatter_edges_kernel<<<(E + 255) / 256, 256, 0, stream>>>(esrc, edst, cursor, elist, E);

    // all prep in one launch (2500 + 256 + 16 + 512 blocks)
    prep_all<<<3284, 256, 0, stream>>>(x, W0, W1, a_src1, a_dst1,
                                       xb, W0T, v1, W1pT);

    // layer 0
    {
        dim3 grid(4, (NN + 63) / 64);
        gemm_bf16_v3<<<grid, 256, 0, stream>>>(xb, W0T, nullptr, h0b, nullptr, nullptr,
                                               NN, 256, 256, 1.0f);
    }
    score0_wave<<<NN / 4, 256, 0, stream>>>(
        (const unsigned short*)h0b, a_src0, a_dst0, s0);
    agg0_fused<<<NN / 4, 256, 0, stream>>>(
        (const unsigned short*)h0b, s0, offsets, counts, elist, h_gat0);
    bn_stats_kernel<<<256, 256, 0, stream>>>(h_gat0, stats0, NN);
    bnapply_score1<<<NN, 256, 0, stream>>>(h_gat0, stats0, g0, be0, v1, hactb, s1);

    // layer 1
    agg1_fused<<<NN / 4, 256, 0, stream>>>(
        (const unsigned short*)hactb, s1, offsets, counts, elist, agg1bf);
    {
        dim3 grid(4, (NN + 63) / 64);
        gemm_bf16_v3<<<grid, 256, 0, stream>>>(agg1bf, W1pT, out1, nullptr, nullptr, stats1,
                                               NN, 256, 2048, 0.125f);
    }

    // BN + ELU + residual + classifier, fused
    bnapply_cls<<<NN, 256, 0, stream>>>(out1, stats1, g1, be1,
                                        (const unsigned short*)hactb, Wc, bc, out);
}

// Round 9
// 272.359 us; speedup vs baseline: 1.2030x; 1.0680x over previous
//
#include <hip/hip_runtime.h>
#include <math.h>

#define NN 10000
#define HEADS 8
#define NCLS 40
#define CHK 64
#define LOG2E 1.4426950408889634f

typedef __attribute__((ext_vector_type(8))) short short8;
typedef __attribute__((ext_vector_type(4))) float floatx4;

static __device__ __forceinline__ short f2bf(float f) {
    unsigned u = __builtin_bit_cast(unsigned, f);
    unsigned r = (u + 0x7fff + ((u >> 16) & 1)) >> 16;
    return (short)r;
}
static __device__ __forceinline__ float bf2f(unsigned short u) {
    unsigned x = ((unsigned)u) << 16;
    return __builtin_bit_cast(float, x);
}
static __device__ __forceinline__ void gl2lds16(const void* g, void* l) {
    __builtin_amdgcn_global_load_lds(
        (const __attribute__((address_space(1))) unsigned int*)g,
        (__attribute__((address_space(3))) unsigned int*)l, 16, 0, 0);
}

// ---------------- bf16 MFMA GEMM v3: BK=64, XOR-swizzled LDS, optional stats epilogue ----
__global__ __launch_bounds__(256) void gemm_bf16_v3(
    const short* __restrict__ A, const short* __restrict__ Bt,
    float* __restrict__ C, short* __restrict__ Cbf, const float* __restrict__ bias,
    float* __restrict__ stats, int M, int Nn, int K, float alpha)
{
    __shared__ short As[64 * 64];
    __shared__ short Bs[64 * 64];
    const int tid = threadIdx.x;
    const int w = tid >> 6, L = tid & 63;
    const int quad = L >> 4, lr = L & 15;
    const int col0 = blockIdx.x * 64, row0 = blockIdx.y * 64;

    const int srow = w * 16 + (L >> 3);
    const int schunk = (L & 7) ^ (L >> 3);
    int ga0 = row0 + srow;     if (ga0 > M - 1)  ga0 = M - 1;
    int ga1 = row0 + srow + 8; if (ga1 > M - 1)  ga1 = M - 1;
    int gb0 = col0 + srow;     if (gb0 > Nn - 1) gb0 = Nn - 1;
    int gb1 = col0 + srow + 8; if (gb1 > Nn - 1) gb1 = Nn - 1;
    const short* agp0 = A + (size_t)ga0 * K + schunk * 8;
    const short* agp1 = A + (size_t)ga1 * K + schunk * 8;
    const short* bgp0 = Bt + (size_t)gb0 * K + schunk * 8;
    const short* bgp1 = Bt + (size_t)gb1 * K + schunk * 8;
    short* alp0 = &As[w * 1024];
    short* alp1 = &As[w * 1024 + 512];
    short* blp0 = &Bs[w * 1024];
    short* blp1 = &Bs[w * 1024 + 512];

    floatx4 acc[4];
    const floatx4 zf = {0.f, 0.f, 0.f, 0.f};
    #pragma unroll
    for (int i = 0; i < 4; i++) acc[i] = zf;

    for (int k0 = 0; k0 < K; k0 += 64) {
        gl2lds16(agp0 + k0, alp0);
        gl2lds16(agp1 + k0, alp1);
        gl2lds16(bgp0 + k0, blp0);
        gl2lds16(bgp1 + k0, blp1);
        __syncthreads();
        #pragma unroll
        for (int ks = 0; ks < 2; ks++) {
            const int sl = ((ks * 4 + quad) ^ (lr & 7)) * 8;
            short8 bfr = *(const short8*)&Bs[(w * 16 + lr) * 64 + sl];
            #pragma unroll
            for (int i = 0; i < 4; i++) {
                short8 afr = *(const short8*)&As[(i * 16 + lr) * 64 + sl];
                acc[i] = __builtin_amdgcn_mfma_f32_16x16x32_bf16(afr, bfr, acc[i], 0, 0, 0);
            }
        }
        __syncthreads();
    }
    const int ccol = col0 + w * 16 + lr;
    float s = 0.f, s2 = 0.f;
    if (ccol < Nn) {
        float bv = bias ? bias[ccol] : 0.f;
        #pragma unroll
        for (int i = 0; i < 4; i++) {
            #pragma unroll
            for (int r = 0; r < 4; r++) {
                int crow = row0 + i * 16 + quad * 4 + r;
                if (crow < M) {
                    float v = alpha * acc[i][r] + bv;
                    if (C)   C[(size_t)crow * Nn + ccol] = v;
                    if (Cbf) Cbf[(size_t)crow * Nn + ccol] = f2bf(v);
                    s += v; s2 += v * v;
                }
            }
        }
    }
    if (stats) {   // 157 y-blocks only -> acceptable contention
        s  += __shfl_xor(s, 16, 64);  s  += __shfl_xor(s, 32, 64);
        s2 += __shfl_xor(s2, 16, 64); s2 += __shfl_xor(s2, 32, 64);
        if (L < 16 && ccol < Nn) {
            atomicAdd(&stats[ccol], s);
            atomicAdd(&stats[256 + ccol], s2);
        }
    }
}

// ---------------- CSR build ----------------
__global__ __launch_bounds__(1024) void scan_kernel(
    int* counts, int* offsets, int* cursor, int* elist, int n)
{
    const int P = (n + 1023) >> 10;
    __shared__ int wsum[16];
    int tid = threadIdx.x, lane = tid & 63, wid = tid >> 6;
    int base = tid * P;
    int local[16];
    int deg[16];
    int s = 0;
    for (int j = 0; j < P; j++) {
        int i = base + j;
        local[j] = s;
        deg[j] = (i < n) ? counts[i] + 1 : 0;   // +1 self-loop
        s += deg[j];
    }
    int inc = s;
    #pragma unroll
    for (int off = 1; off < 64; off <<= 1) {
        int tv = __shfl_up(inc, off, 64);
        if (lane >= off) inc += tv;
    }
    if (lane == 63) wsum[wid] = inc;
    __syncthreads();
    if (tid < 16) {
        int v = wsum[tid];
        int winc = v;
        #pragma unroll
        for (int off = 1; off < 16; off <<= 1) {
            int tv = __shfl_up(winc, off, 16);
            if (tid >= off) winc += tv;
        }
        wsum[tid] = winc - v;
    }
    __syncthreads();
    int excl = inc - s + wsum[wid];
    for (int j = 0; j < P; j++) {
        int i = base + j;
        if (i < n) {
            int o = excl + local[j];
            counts[i] = deg[j];
            offsets[i] = o;
            elist[o] = i;       // self-loop in slot 0
            cursor[i] = o + 1;
        }
    }
}

__global__ void scatter_edges_kernel(const int* __restrict__ src, const int* __restrict__ dst,
                                     int* cursor, int* elist, int E) {
    int e = blockIdx.x * 256 + threadIdx.x;
    if (e < E) {
        int d = dst[e];
        int pos = atomicAdd(&cursor[d], 1);
        elist[pos] = src[e];
    }
}

// ---------------- all weight/input prep + edge counting in one launch ----------------
__global__ __launch_bounds__(256) void prep_count(
    const float* __restrict__ x, const float* __restrict__ W0,
    const float* __restrict__ W1, const float* __restrict__ a_src1,
    const float* __restrict__ a_dst1, const float* __restrict__ Wc,
    const int* __restrict__ edst, int E,
    short* __restrict__ xb, short* __restrict__ W0T, float* __restrict__ v1,
    short* __restrict__ W1pT, short* __restrict__ WcT, int* __restrict__ counts)
{
    __shared__ float tile[32][33];
    const int b = blockIdx.x, t = threadIdx.x;
    if (b < 2500) {                 // cast x -> bf16 (x4 vectorized)
        int i = b * 256 + t;
        floatx4 v = ((const floatx4*)x)[i];
        short4 o = {f2bf(v[0]), f2bf(v[1]), f2bf(v[2]), f2bf(v[3])};
        ((short4*)xb)[i] = o;
    } else if (b < 2756) {          // W0T [256][256]
        int o = b - 2500;
        W0T[o * 256 + t] = f2bf(W0[t * 256 + o]);
    } else if (b < 2772) {          // v1 = folded W1·a  [256 f][16 j]
        int idx = (b - 2756) * 256 + t;
        int f = idx >> 4, j = idx & 15;
        int h = j & 7;
        const float* a = (j < 8) ? a_src1 : a_dst1;
        float s = 0.f;
        for (int c = 0; c < 256; c++)
            s += W1[f * 2048 + h * 256 + c] * a[h * 256 + c];
        v1[idx] = s;
    } else if (b < 3284) {          // W1pT bf16 [256 c][2048 hf]
        int id = b - 2772;
        int h = id >> 6, f0 = ((id >> 3) & 7) * 32, c0 = (id & 7) * 32;
        int tx = t & 31, ty = t >> 5;
        for (int r = ty; r < 32; r += 8)
            tile[r][tx] = W1[(size_t)(f0 + r) * 2048 + h * 256 + c0 + tx];
        __syncthreads();
        for (int r = ty; r < 32; r += 8)
            W1pT[(size_t)(c0 + r) * 2048 + h * 256 + f0 + tx] = f2bf(tile[tx][r]);
    } else if (b < 3324) {          // WcT bf16 [40][256]
        int o = b - 3284;
        WcT[o * 256 + t] = f2bf(Wc[t * 40 + o]);
    } else {                        // count edges
        int e = (b - 3324) * 256 + t;
        if (e < E) atomicAdd(&counts[edst[e]], 1);
    }
}

// ---------------- layer-0 node scores: wave per node ----------------
__global__ __launch_bounds__(256) void score0_wave(
    const unsigned short* __restrict__ h0b, const float* __restrict__ a_src,
    const float* __restrict__ a_dst, float* __restrict__ s0)
{
    const int wid = threadIdx.x >> 6, L = threadIdx.x & 63;
    const int n = blockIdx.x * 4 + wid;   // NN % 4 == 0
    ushort4 vv = *(const ushort4*)(h0b + (size_t)n * 256 + 4 * L);
    floatx4 as = *(const floatx4*)(a_src + 4 * L);
    floatx4 ad = *(const floatx4*)(a_dst + 4 * L);
    float v0 = bf2f(vv.x), v1_ = bf2f(vv.y), v2 = bf2f(vv.z), v3 = bf2f(vv.w);
    float ps = v0 * as[0] + v1_ * as[1] + v2 * as[2] + v3 * as[3];
    float pd = v0 * ad[0] + v1_ * ad[1] + v2 * ad[2] + v3 * ad[3];
    #pragma unroll
    for (int off = 1; off < 8; off <<= 1) {
        ps += __shfl_xor(ps, off, 64);
        pd += __shfl_xor(pd, off, 64);
    }
    if ((L & 7) == 0) {
        s0[n * 16 + (L >> 3)] = ps;
        s0[n * 16 + 8 + (L >> 3)] = pd;
    }
}

// ---------------- fused softmax(no-max)+aggregate, layer 0 (barrier-free) ----------------
__global__ __launch_bounds__(256) void agg0_fused(
    const unsigned short* __restrict__ h0b, const float* __restrict__ s0,
    const int* __restrict__ offsets, const int* __restrict__ counts,
    const int* __restrict__ elist, float* __restrict__ out)
{
    __shared__ float pw_s[4][CHK * 8];
    __shared__ int   sn_s[4][CHK];
    const int wid = threadIdx.x >> 6, L = threadIdx.x & 63;
    const int n = blockIdx.x * 4 + wid;   // NN % 4 == 0
    float* pw = pw_s[wid];
    int*   sw = sn_s[wid];
    const int deg = counts[n], start = offsets[n];
    const int hL = L >> 3;

    floatx4 sda = *(const floatx4*)(s0 + n * 16 + 8);
    floatx4 sdb = *(const floatx4*)(s0 + n * 16 + 12);
    float sd[8] = {sda[0], sda[1], sda[2], sda[3], sdb[0], sdb[1], sdb[2], sdb[3]};
    float lp[8] = {0.f, 0.f, 0.f, 0.f, 0.f, 0.f, 0.f, 0.f};
    float a0 = 0.f, a1 = 0.f, a2 = 0.f, a3 = 0.f;

    for (int e0 = 0; e0 < deg; e0 += CHK) {
        int ch = deg - e0; if (ch > CHK) ch = CHK;
        if (L < ch) {
            int sn = elist[start + e0 + L];
            sw[L] = sn;
            floatx4 ssa = *(const floatx4*)(s0 + sn * 16);
            floatx4 ssb = *(const floatx4*)(s0 + sn * 16 + 4);
            float ss[8] = {ssa[0], ssa[1], ssa[2], ssa[3], ssb[0], ssb[1], ssb[2], ssb[3]};
            float p[8];
            #pragma unroll
            for (int h = 0; h < 8; h++) {
                float v = ss[h] + sd[h];
                v = (v > 0.f) ? v : 0.2f * v;
                p[h] = exp2f(v * LOG2E);
                lp[h] += p[h];
            }
            floatx4 p0 = {p[0], p[1], p[2], p[3]};
            floatx4 p1 = {p[4], p[5], p[6], p[7]};
            *(floatx4*)&pw[L * 8] = p0;
            *(floatx4*)&pw[L * 8 + 4] = p1;
        }
        for (int e = 0; e < ch; e++) {
            float wgt = pw[e * 8 + hL];
            ushort4 vv = *(const ushort4*)(h0b + (size_t)sw[e] * 256 + 4 * L);
            a0 += wgt * bf2f(vv.x);
            a1 += wgt * bf2f(vv.y);
            a2 += wgt * bf2f(vv.z);
            a3 += wgt * bf2f(vv.w);
        }
    }
    #pragma unroll
    for (int off = 1; off < 64; off <<= 1)
        #pragma unroll
        for (int h = 0; h < 8; h++)
            lp[h] += __shfl_xor(lp[h], off, 64);
    float inv = 1.f / lp[hL];
    floatx4 o = {a0 * inv, a1 * inv, a2 * inv, a3 * inv};
    *(floatx4*)(out + (size_t)n * 256 + 4 * L) = o;
}

// ---------------- layer-1 aggregate: 2 waves per node (4 heads each), barrier-free ------
__global__ __launch_bounds__(256) void agg1_half(
    const unsigned short* __restrict__ hb, const float* __restrict__ s1,
    const int* __restrict__ offsets, const int* __restrict__ counts,
    const int* __restrict__ elist, short* __restrict__ aggout)
{
    __shared__ float pw_s[4][CHK * 4];
    __shared__ int   sn_s[4][CHK];
    const int wid = threadIdx.x >> 6, L = threadIdx.x & 63;
    const int n = blockIdx.x * 2 + (wid >> 1);   // NN % 2 == 0
    const int hg = wid & 1;                       // head group: heads hg*4 .. hg*4+3
    float* pw = pw_s[wid];
    int*   sw = sn_s[wid];
    const int deg = counts[n], start = offsets[n];

    floatx4 sd4 = *(const floatx4*)(s1 + n * 16 + 8 + hg * 4);
    float lp[4] = {0.f, 0.f, 0.f, 0.f};
    float acc[4][4];
    #pragma unroll
    for (int h = 0; h < 4; h++)
        #pragma unroll
        for (int f = 0; f < 4; f++) acc[h][f] = 0.f;

    for (int e0 = 0; e0 < deg; e0 += CHK) {
        int ch = deg - e0; if (ch > CHK) ch = CHK;
        if (L < ch) {
            int sn = elist[start + e0 + L];
            sw[L] = sn;
            floatx4 ss4 = *(const floatx4*)(s1 + sn * 16 + hg * 4);
            floatx4 p4;
            #pragma unroll
            for (int h = 0; h < 4; h++) {
                float v = ss4[h] + sd4[h];
                v = (v > 0.f) ? v : 0.2f * v;
                float p = exp2f(v * LOG2E);
                p4[h] = p;
                lp[h] += p;
            }
            *(floatx4*)&pw[L * 4] = p4;
        }
        for (int e = 0; e < ch; e++) {
            floatx4 pv = *(const floatx4*)&pw[e * 4];
            ushort4 vv = *(const ushort4*)(hb + (size_t)sw[e] * 256 + 4 * L);
            float v0 = bf2f(vv.x), v1_ = bf2f(vv.y), v2 = bf2f(vv.z), v3 = bf2f(vv.w);
            #pragma unroll
            for (int h = 0; h < 4; h++) {
                acc[h][0] += pv[h] * v0;
                acc[h][1] += pv[h] * v1_;
                acc[h][2] += pv[h] * v2;
                acc[h][3] += pv[h] * v3;
            }
        }
    }
    #pragma unroll
    for (int off = 1; off < 64; off <<= 1)
        #pragma unroll
        for (int h = 0; h < 4; h++)
            lp[h] += __shfl_xor(lp[h], off, 64);
    #pragma unroll
    for (int h = 0; h < 4; h++) {
        float inv = 1.f / lp[h];
        short4 o = {f2bf(acc[h][0] * inv), f2bf(acc[h][1] * inv),
                    f2bf(acc[h][2] * inv), f2bf(acc[h][3] * inv)};
        *(short4*)(aggout + (size_t)n * 2048 + (hg * 4 + h) * 256 + 4 * L) = o;
    }
}

// ---------------- batchnorm stats (256 blocks -> low atomic contention) ----------------
__global__ __launch_bounds__(256) void bn_stats_kernel(const float* __restrict__ x, float* stats, int n) {
    int t = threadIdx.x;
    float s = 0.f, s2 = 0.f;
    for (int r = blockIdx.x; r < n; r += gridDim.x) {
        float v = x[(size_t)r * 256 + t];
        s += v; s2 += v * v;
    }
    atomicAdd(&stats[t], s);
    atomicAdd(&stats[256 + t], s2);
}

// ---------------- BN + ELU + bf16 write + layer-1 score, one block per node ----------------
__global__ __launch_bounds__(256) void bnapply_score1(
    const float* __restrict__ xg, const float* __restrict__ stats,
    const float* __restrict__ g, const float* __restrict__ be,
    const float* __restrict__ v1, short* __restrict__ hactb, float* __restrict__ s1)
{
    __shared__ float row[256];
    __shared__ float part[16][17];
    const int n = blockIdx.x, t = threadIdx.x;
    const float invN = 1.0f / NN;
    float mu = stats[t] * invN;
    float var = stats[256 + t] * invN - mu * mu;
    float v = g[t] * (xg[(size_t)n * 256 + t] - mu) * rsqrtf(var + 1e-5f) + be[t];
    v = (v > 0.f) ? v : (expf(v) - 1.f);   // ELU
    hactb[(size_t)n * 256 + t] = f2bf(v);
    row[t] = v;
    __syncthreads();
    int j = t & 15, f0 = t >> 4;
    float p = 0.f;
    #pragma unroll
    for (int k = 0; k < 16; k++)
        p += row[f0 * 16 + k] * v1[(f0 * 16 + k) * 16 + j];
    part[f0][j] = p;
    __syncthreads();
    if (t < 16) {
        float s = 0.f;
        #pragma unroll
        for (int k = 0; k < 16; k++) s += part[k][t];
        s1[n * 16 + t] = s;
    }
}

// ---------------- BN + ELU + residual (bf16) -> bf16, elementwise ----------------
__global__ __launch_bounds__(256) void bn_apply_kernel(
    const float* __restrict__ x, const float* __restrict__ stats,
    const float* __restrict__ g, const float* __restrict__ be,
    const unsigned short* __restrict__ resid, short* __restrict__ ybf, int total)
{
    int i = blockIdx.x * 256 + threadIdx.x;
    if (i >= total) return;
    int c = i & 255;
    const float invN = 1.0f / NN;
    float mu = stats[c] * invN;
    float var = stats[256 + c] * invN - mu * mu;
    float v = g[c] * (x[i] - mu) * rsqrtf(var + 1e-5f) + be[c];
    v = (v > 0.f) ? v : (expf(v) - 1.f);   // ELU
    v += bf2f(resid[i]);
    ybf[i] = f2bf(v);
}

// ---------------- launch ----------------
extern "C" void kernel_launch(void* const* d_in, const int* in_sizes, int n_in,
                              void* d_out, int out_size, void* d_ws, size_t ws_size,
                              hipStream_t stream) {
    const float* x      = (const float*)d_in[0];
    const int*   eidx   = (const int*)d_in[1];
    const float* W0     = (const float*)d_in[2];
    const float* a_src0 = (const float*)d_in[3];
    const float* a_dst0 = (const float*)d_in[4];
    const float* g0     = (const float*)d_in[6];
    const float* be0    = (const float*)d_in[7];
    const float* W1     = (const float*)d_in[8];
    const float* a_src1 = (const float*)d_in[9];
    const float* a_dst1 = (const float*)d_in[10];
    const float* g1     = (const float*)d_in[12];
    const float* be1    = (const float*)d_in[13];
    const float* Wc     = (const float*)d_in[14];
    const float* bc     = (const float*)d_in[15];
    float* out = (float*)d_out;

    const int E = in_sizes[1] / 2;
    const int* esrc = eidx;
    const int* edst = eidx + E;

    char* ws = (char*)d_ws;
    size_t off = 0;
    auto alloc = [&](size_t bytes) {
        void* p = ws + off;
        off += (bytes + 255) & ~(size_t)255;
        return p;
    };
    // stats + counts contiguous -> single memset
    float* stats   = (float*)alloc(1024 * 4);
    int*   counts  = (int*)alloc(NN * 4);
    float* out1    = (float*)alloc((size_t)NN * 256 * 4);
    short* h0b     = (short*)alloc((size_t)NN * 256 * 2);
    short* xb      = (short*)alloc((size_t)NN * 256 * 2);
    float* s0      = (float*)alloc((size_t)NN * 16 * 4);
    float* s1      = (float*)alloc((size_t)NN * 16 * 4);
    float* v1      = (float*)alloc(4096 * 4);
    float* h_gat0  = (float*)alloc((size_t)NN * 256 * 4);
    short* hactb   = (short*)alloc((size_t)NN * 256 * 2);
    short* agg1bf  = (short*)alloc((size_t)NN * 2048 * 2);
    short* W0T     = (short*)alloc((size_t)256 * 256 * 2);
    short* W1pT    = (short*)alloc((size_t)256 * 2048 * 2);
    short* WcT     = (short*)alloc((size_t)64 * 256 * 2);
    short* hfinbf  = (short*)alloc((size_t)NN * 256 * 2);
    int* offsets   = (int*)alloc((NN + 16) * 4);
    int* cursor    = (int*)alloc(NN * 4);
    int* elist     = (int*)alloc((size_t)(E + NN) * 4);

    float* stats0 = stats;
    float* stats1 = stats + 512;

    hipMemsetAsync(stats, 0, 1024 * 4 + NN * 4, stream);   // stats0+stats1+counts

    // prep + edge counting in one launch
    const int cntBlocks = (E + 255) / 256;
    prep_count<<<3324 + cntBlocks, 256, 0, stream>>>(
        x, W0, W1, a_src1, a_dst1, Wc, edst, E,
        xb, W0T, v1, W1pT, WcT, counts);

    scan_kernel<<<1, 1024, 0, stream>>>(counts, offsets, cursor, elist, NN);
    scatter_edges_kernel<<<cntBlocks, 256, 0, stream>>>(esrc, edst, cursor, elist, E);

    // layer 0
    {
        dim3 grid(4, (NN + 63) / 64);
        gemm_bf16_v3<<<grid, 256, 0, stream>>>(xb, W0T, nullptr, h0b, nullptr, nullptr,
                                               NN, 256, 256, 1.0f);
    }
    score0_wave<<<NN / 4, 256, 0, stream>>>(
        (const unsigned short*)h0b, a_src0, a_dst0, s0);
    agg0_fused<<<NN / 4, 256, 0, stream>>>(
        (const unsigned short*)h0b, s0, offsets, counts, elist, h_gat0);
    bn_stats_kernel<<<256, 256, 0, stream>>>(h_gat0, stats0, NN);
    bnapply_score1<<<NN, 256, 0, stream>>>(h_gat0, stats0, g0, be0, v1, hactb, s1);

    // layer 1
    agg1_half<<<NN / 2, 256, 0, stream>>>(
        (const unsigned short*)hactb, s1, offsets, counts, elist, agg1bf);
    {
        dim3 grid(4, (NN + 63) / 64);
        gemm_bf16_v3<<<grid, 256, 0, stream>>>(agg1bf, W1pT, out1, nullptr, nullptr, stats1,
                                               NN, 256, 2048, 0.125f);
    }
    bn_apply_kernel<<<(NN * 256 + 255) / 256, 256, 0, stream>>>(
        out1, stats1, g1, be1, (const unsigned short*)hactb, hfinbf, NN * 256);

    // classifier (bf16 MFMA)
    {
        dim3 grid(1, (NN + 63) / 64);
        gemm_bf16_v3<<<grid, 256, 0, stream>>>(hfinbf, WcT, out, nullptr, bc, nullptr,
                                               NN, NCLS, 256, 1.0f);
    }
}

// Round 10
// 271.861 us; speedup vs baseline: 1.2052x; 1.0018x over previous
//
#include <hip/hip_runtime.h>
#include <math.h>

#define NN 10000
#define HEADS 8
#define NCLS 40
#define CHK 64
#define LOG2E 1.4426950408889634f

typedef __attribute__((ext_vector_type(8))) short short8;
typedef __attribute__((ext_vector_type(4))) float floatx4;

static __device__ __forceinline__ short f2bf(float f) {
    unsigned u = __builtin_bit_cast(unsigned, f);
    unsigned r = (u + 0x7fff + ((u >> 16) & 1)) >> 16;
    return (short)r;
}
static __device__ __forceinline__ float bf2f(unsigned short u) {
    unsigned x = ((unsigned)u) << 16;
    return __builtin_bit_cast(float, x);
}
static __device__ __forceinline__ void gl2lds16(const void* g, void* l) {
    __builtin_amdgcn_global_load_lds(
        (const __attribute__((address_space(1))) unsigned int*)g,
        (__attribute__((address_space(3))) unsigned int*)l, 16, 0, 0);
}

// ---------------- bf16 MFMA GEMM wide: BM=64, BN=128, BK=64, XOR-swizzled LDS ----------
// Halves A-refetch vs BN=64 (A rows read once per 128 output cols). grid = (Nn/128, ceil(M/64)).
__global__ __launch_bounds__(256) void gemm_bf16_w128(
    const short* __restrict__ A, const short* __restrict__ Bt,
    float* __restrict__ C, short* __restrict__ Cbf,
    float* __restrict__ stats, int M, int Nn, int K, float alpha)
{
    __shared__ short As[64 * 64];    // 8 KB
    __shared__ short Bs[128 * 64];   // 16 KB
    const int tid = threadIdx.x;
    const int w = tid >> 6, L = tid & 63;
    const int quad = L >> 4, lr = L & 15;
    const int col0 = blockIdx.x * 128, row0 = blockIdx.y * 64;

    const int schunk = (L & 7) ^ (L >> 3);   // (row&7)==(L>>3) for all staged rows
    // A: wave stages rows w*16 + (L>>3) + {0,8}
    const int sarow = w * 16 + (L >> 3);
    int ga0 = row0 + sarow;     if (ga0 > M - 1) ga0 = M - 1;
    int ga1 = row0 + sarow + 8; if (ga1 > M - 1) ga1 = M - 1;
    const short* agp0 = A + (size_t)ga0 * K + schunk * 8;
    const short* agp1 = A + (size_t)ga1 * K + schunk * 8;
    short* alp0 = &As[w * 1024];
    short* alp1 = &As[w * 1024 + 512];
    // B: wave stages rows w*32 + (L>>3) + {0,8,16,24}
    const int sbrow = w * 32 + (L >> 3);
    int gb[4];
    #pragma unroll
    for (int c = 0; c < 4; c++) {
        gb[c] = col0 + sbrow + c * 8;
        if (gb[c] > Nn - 1) gb[c] = Nn - 1;
    }
    const short* bgp0 = Bt + (size_t)gb[0] * K + schunk * 8;
    const short* bgp1 = Bt + (size_t)gb[1] * K + schunk * 8;
    const short* bgp2 = Bt + (size_t)gb[2] * K + schunk * 8;
    const short* bgp3 = Bt + (size_t)gb[3] * K + schunk * 8;
    short* blp0 = &Bs[w * 2048];
    short* blp1 = &Bs[w * 2048 + 512];
    short* blp2 = &Bs[w * 2048 + 1024];
    short* blp3 = &Bs[w * 2048 + 1536];

    floatx4 acc[4][2];
    const floatx4 zf = {0.f, 0.f, 0.f, 0.f};
    #pragma unroll
    for (int i = 0; i < 4; i++)
        #pragma unroll
        for (int j = 0; j < 2; j++) acc[i][j] = zf;

    for (int k0 = 0; k0 < K; k0 += 64) {
        gl2lds16(agp0 + k0, alp0);
        gl2lds16(agp1 + k0, alp1);
        gl2lds16(bgp0 + k0, blp0);
        gl2lds16(bgp1 + k0, blp1);
        gl2lds16(bgp2 + k0, blp2);
        gl2lds16(bgp3 + k0, blp3);
        __syncthreads();
        #pragma unroll
        for (int ks = 0; ks < 2; ks++) {
            const int sl = ((ks * 4 + quad) ^ (lr & 7)) * 8;
            short8 bfr[2];
            #pragma unroll
            for (int j = 0; j < 2; j++)
                bfr[j] = *(const short8*)&Bs[(w * 32 + j * 16 + lr) * 64 + sl];
            #pragma unroll
            for (int i = 0; i < 4; i++) {
                short8 afr = *(const short8*)&As[(i * 16 + lr) * 64 + sl];
                #pragma unroll
                for (int j = 0; j < 2; j++)
                    acc[i][j] = __builtin_amdgcn_mfma_f32_16x16x32_bf16(afr, bfr[j], acc[i][j], 0, 0, 0);
            }
        }
        __syncthreads();
    }
    float s[2] = {0.f, 0.f}, s2[2] = {0.f, 0.f};
    #pragma unroll
    for (int j = 0; j < 2; j++) {
        int ccol = col0 + w * 32 + j * 16 + lr;
        if (ccol >= Nn) continue;
        #pragma unroll
        for (int i = 0; i < 4; i++) {
            #pragma unroll
            for (int r = 0; r < 4; r++) {
                int crow = row0 + i * 16 + quad * 4 + r;
                if (crow < M) {
                    float v = alpha * acc[i][j][r];
                    if (C)   C[(size_t)crow * Nn + ccol] = v;
                    if (Cbf) Cbf[(size_t)crow * Nn + ccol] = f2bf(v);
                    s[j] += v; s2[j] += v * v;
                }
            }
        }
    }
    if (stats) {   // 314 blocks -> acceptable contention
        #pragma unroll
        for (int j = 0; j < 2; j++) {
            s[j]  += __shfl_xor(s[j], 16, 64);  s[j]  += __shfl_xor(s[j], 32, 64);
            s2[j] += __shfl_xor(s2[j], 16, 64); s2[j] += __shfl_xor(s2[j], 32, 64);
        }
        if (L < 16) {
            #pragma unroll
            for (int j = 0; j < 2; j++) {
                int ccol = col0 + w * 32 + j * 16 + L;
                if (ccol < Nn) {
                    atomicAdd(&stats[ccol], s[j]);
                    atomicAdd(&stats[256 + ccol], s2[j]);
                }
            }
        }
    }
}

// ---------------- bf16 MFMA GEMM v3 (BN=64) -- classifier only ----------
__global__ __launch_bounds__(256) void gemm_bf16_v3(
    const short* __restrict__ A, const short* __restrict__ Bt,
    float* __restrict__ C, const float* __restrict__ bias,
    int M, int Nn, int K, float alpha)
{
    __shared__ short As[64 * 64];
    __shared__ short Bs[64 * 64];
    const int tid = threadIdx.x;
    const int w = tid >> 6, L = tid & 63;
    const int quad = L >> 4, lr = L & 15;
    const int col0 = blockIdx.x * 64, row0 = blockIdx.y * 64;

    const int srow = w * 16 + (L >> 3);
    const int schunk = (L & 7) ^ (L >> 3);
    int ga0 = row0 + srow;     if (ga0 > M - 1)  ga0 = M - 1;
    int ga1 = row0 + srow + 8; if (ga1 > M - 1)  ga1 = M - 1;
    int gb0 = col0 + srow;     if (gb0 > Nn - 1) gb0 = Nn - 1;
    int gb1 = col0 + srow + 8; if (gb1 > Nn - 1) gb1 = Nn - 1;
    const short* agp0 = A + (size_t)ga0 * K + schunk * 8;
    const short* agp1 = A + (size_t)ga1 * K + schunk * 8;
    const short* bgp0 = Bt + (size_t)gb0 * K + schunk * 8;
    const short* bgp1 = Bt + (size_t)gb1 * K + schunk * 8;
    short* alp0 = &As[w * 1024];
    short* alp1 = &As[w * 1024 + 512];
    short* blp0 = &Bs[w * 1024];
    short* blp1 = &Bs[w * 1024 + 512];

    floatx4 acc[4];
    const floatx4 zf = {0.f, 0.f, 0.f, 0.f};
    #pragma unroll
    for (int i = 0; i < 4; i++) acc[i] = zf;

    for (int k0 = 0; k0 < K; k0 += 64) {
        gl2lds16(agp0 + k0, alp0);
        gl2lds16(agp1 + k0, alp1);
        gl2lds16(bgp0 + k0, blp0);
        gl2lds16(bgp1 + k0, blp1);
        __syncthreads();
        #pragma unroll
        for (int ks = 0; ks < 2; ks++) {
            const int sl = ((ks * 4 + quad) ^ (lr & 7)) * 8;
            short8 bfr = *(const short8*)&Bs[(w * 16 + lr) * 64 + sl];
            #pragma unroll
            for (int i = 0; i < 4; i++) {
                short8 afr = *(const short8*)&As[(i * 16 + lr) * 64 + sl];
                acc[i] = __builtin_amdgcn_mfma_f32_16x16x32_bf16(afr, bfr, acc[i], 0, 0, 0);
            }
        }
        __syncthreads();
    }
    const int ccol = col0 + w * 16 + lr;
    if (ccol < Nn) {
        float bv = bias ? bias[ccol] : 0.f;
        #pragma unroll
        for (int i = 0; i < 4; i++) {
            #pragma unroll
            for (int r = 0; r < 4; r++) {
                int crow = row0 + i * 16 + quad * 4 + r;
                if (crow < M) C[(size_t)crow * Nn + ccol] = alpha * acc[i][r] + bv;
            }
        }
    }
}

// ---------------- CSR build ----------------
__global__ __launch_bounds__(1024) void scan_kernel(
    int* counts, int* offsets, int* cursor, int* elist, int n)
{
    const int P = (n + 1023) >> 10;
    __shared__ int wsum[16];
    int tid = threadIdx.x, lane = tid & 63, wid = tid >> 6;
    int base = tid * P;
    int local[16];
    int deg[16];
    int s = 0;
    for (int j = 0; j < P; j++) {
        int i = base + j;
        local[j] = s;
        deg[j] = (i < n) ? counts[i] + 1 : 0;   // +1 self-loop
        s += deg[j];
    }
    int inc = s;
    #pragma unroll
    for (int off = 1; off < 64; off <<= 1) {
        int tv = __shfl_up(inc, off, 64);
        if (lane >= off) inc += tv;
    }
    if (lane == 63) wsum[wid] = inc;
    __syncthreads();
    if (tid < 16) {
        int v = wsum[tid];
        int winc = v;
        #pragma unroll
        for (int off = 1; off < 16; off <<= 1) {
            int tv = __shfl_up(winc, off, 16);
            if (tid >= off) winc += tv;
        }
        wsum[tid] = winc - v;
    }
    __syncthreads();
    int excl = inc - s + wsum[wid];
    for (int j = 0; j < P; j++) {
        int i = base + j;
        if (i < n) {
            int o = excl + local[j];
            counts[i] = deg[j];
            offsets[i] = o;
            elist[o] = i;       // self-loop in slot 0
            cursor[i] = o + 1;
        }
    }
}

__global__ void scatter_edges_kernel(const int* __restrict__ src, const int* __restrict__ dst,
                                     int* cursor, int* elist, int E) {
    int e = blockIdx.x * 256 + threadIdx.x;
    if (e < E) {
        int d = dst[e];
        int pos = atomicAdd(&cursor[d], 1);
        elist[pos] = src[e];
    }
}

// ---------------- all weight/input prep + edge counting in one launch ----------------
__global__ __launch_bounds__(256) void prep_count(
    const float* __restrict__ x, const float* __restrict__ W0,
    const float* __restrict__ W1, const float* __restrict__ a_src1,
    const float* __restrict__ a_dst1, const float* __restrict__ Wc,
    const int* __restrict__ edst, int E,
    short* __restrict__ xb, short* __restrict__ W0T, float* __restrict__ v1,
    short* __restrict__ W1pT, short* __restrict__ WcT, int* __restrict__ counts)
{
    __shared__ float tile[32][33];
    const int b = blockIdx.x, t = threadIdx.x;
    if (b < 2500) {                 // cast x -> bf16 (x4 vectorized)
        int i = b * 256 + t;
        floatx4 v = ((const floatx4*)x)[i];
        short4 o = {f2bf(v[0]), f2bf(v[1]), f2bf(v[2]), f2bf(v[3])};
        ((short4*)xb)[i] = o;
    } else if (b < 2756) {          // W0T [256][256]
        int o = b - 2500;
        W0T[o * 256 + t] = f2bf(W0[t * 256 + o]);
    } else if (b < 2772) {          // v1 = folded W1·a  [256 f][16 j]
        int idx = (b - 2756) * 256 + t;
        int f = idx >> 4, j = idx & 15;
        int h = j & 7;
        const float* a = (j < 8) ? a_src1 : a_dst1;
        float s = 0.f;
        for (int c = 0; c < 256; c++)
            s += W1[f * 2048 + h * 256 + c] * a[h * 256 + c];
        v1[idx] = s;
    } else if (b < 3284) {          // W1pT bf16 [256 c][2048 hf]
        int id = b - 2772;
        int h = id >> 6, f0 = ((id >> 3) & 7) * 32, c0 = (id & 7) * 32;
        int tx = t & 31, ty = t >> 5;
        for (int r = ty; r < 32; r += 8)
            tile[r][tx] = W1[(size_t)(f0 + r) * 2048 + h * 256 + c0 + tx];
        __syncthreads();
        for (int r = ty; r < 32; r += 8)
            W1pT[(size_t)(c0 + r) * 2048 + h * 256 + f0 + tx] = f2bf(tile[tx][r]);
    } else if (b < 3324) {          // WcT bf16 [40][256]
        int o = b - 3284;
        WcT[o * 256 + t] = f2bf(Wc[t * 40 + o]);
    } else {                        // count edges
        int e = (b - 3324) * 256 + t;
        if (e < E) atomicAdd(&counts[edst[e]], 1);
    }
}

// ---------------- layer-0 node scores: wave per node ----------------
__global__ __launch_bounds__(256) void score0_wave(
    const unsigned short* __restrict__ h0b, const float* __restrict__ a_src,
    const float* __restrict__ a_dst, float* __restrict__ s0)
{
    const int wid = threadIdx.x >> 6, L = threadIdx.x & 63;
    const int n = blockIdx.x * 4 + wid;   // NN % 4 == 0
    ushort4 vv = *(const ushort4*)(h0b + (size_t)n * 256 + 4 * L);
    floatx4 as = *(const floatx4*)(a_src + 4 * L);
    floatx4 ad = *(const floatx4*)(a_dst + 4 * L);
    float v0 = bf2f(vv.x), v1_ = bf2f(vv.y), v2 = bf2f(vv.z), v3 = bf2f(vv.w);
    float ps = v0 * as[0] + v1_ * as[1] + v2 * as[2] + v3 * as[3];
    float pd = v0 * ad[0] + v1_ * ad[1] + v2 * ad[2] + v3 * ad[3];
    #pragma unroll
    for (int off = 1; off < 8; off <<= 1) {
        ps += __shfl_xor(ps, off, 64);
        pd += __shfl_xor(pd, off, 64);
    }
    if ((L & 7) == 0) {
        s0[n * 16 + (L >> 3)] = ps;
        s0[n * 16 + 8 + (L >> 3)] = pd;
    }
}

// ---------------- fused softmax(no-max)+aggregate, layer 0 (barrier-free) ----------------
__global__ __launch_bounds__(256) void agg0_fused(
    const unsigned short* __restrict__ h0b, const float* __restrict__ s0,
    const int* __restrict__ offsets, const int* __restrict__ counts,
    const int* __restrict__ elist, float* __restrict__ out)
{
    __shared__ float pw_s[4][CHK * 8];
    __shared__ int   sn_s[4][CHK];
    const int wid = threadIdx.x >> 6, L = threadIdx.x & 63;
    const int n = blockIdx.x * 4 + wid;   // NN % 4 == 0
    float* pw = pw_s[wid];
    int*   sw = sn_s[wid];
    const int deg = counts[n], start = offsets[n];
    const int hL = L >> 3;

    floatx4 sda = *(const floatx4*)(s0 + n * 16 + 8);
    floatx4 sdb = *(const floatx4*)(s0 + n * 16 + 12);
    float sd[8] = {sda[0], sda[1], sda[2], sda[3], sdb[0], sdb[1], sdb[2], sdb[3]};
    float lp[8] = {0.f, 0.f, 0.f, 0.f, 0.f, 0.f, 0.f, 0.f};
    float a0 = 0.f, a1 = 0.f, a2 = 0.f, a3 = 0.f;

    for (int e0 = 0; e0 < deg; e0 += CHK) {
        int ch = deg - e0; if (ch > CHK) ch = CHK;
        if (L < ch) {
            int sn = elist[start + e0 + L];
            sw[L] = sn;
            floatx4 ssa = *(const floatx4*)(s0 + sn * 16);
            floatx4 ssb = *(const floatx4*)(s0 + sn * 16 + 4);
            float ss[8] = {ssa[0], ssa[1], ssa[2], ssa[3], ssb[0], ssb[1], ssb[2], ssb[3]};
            float p[8];
            #pragma unroll
            for (int h = 0; h < 8; h++) {
                float v = ss[h] + sd[h];
                v = (v > 0.f) ? v : 0.2f * v;
                p[h] = exp2f(v * LOG2E);
                lp[h] += p[h];
            }
            floatx4 p0 = {p[0], p[1], p[2], p[3]};
            floatx4 p1 = {p[4], p[5], p[6], p[7]};
            *(floatx4*)&pw[L * 8] = p0;
            *(floatx4*)&pw[L * 8 + 4] = p1;
        }
        for (int e = 0; e < ch; e++) {
            float wgt = pw[e * 8 + hL];
            ushort4 vv = *(const ushort4*)(h0b + (size_t)sw[e] * 256 + 4 * L);
            a0 += wgt * bf2f(vv.x);
            a1 += wgt * bf2f(vv.y);
            a2 += wgt * bf2f(vv.z);
            a3 += wgt * bf2f(vv.w);
        }
    }
    #pragma unroll
    for (int off = 1; off < 64; off <<= 1)
        #pragma unroll
        for (int h = 0; h < 8; h++)
            lp[h] += __shfl_xor(lp[h], off, 64);
    float inv = 1.f / lp[hL];
    floatx4 o = {a0 * inv, a1 * inv, a2 * inv, a3 * inv};
    *(floatx4*)(out + (size_t)n * 256 + 4 * L) = o;
}

// ---------------- layer-1 aggregate: 2 waves per node (4 heads each), barrier-free ------
__global__ __launch_bounds__(256) void agg1_half(
    const unsigned short* __restrict__ hb, const float* __restrict__ s1,
    const int* __restrict__ offsets, const int* __restrict__ counts,
    const int* __restrict__ elist, short* __restrict__ aggout)
{
    __shared__ float pw_s[4][CHK * 4];
    __shared__ int   sn_s[4][CHK];
    const int wid = threadIdx.x >> 6, L = threadIdx.x & 63;
    const int n = blockIdx.x * 2 + (wid >> 1);   // NN % 2 == 0
    const int hg = wid & 1;                       // head group: heads hg*4 .. hg*4+3
    float* pw = pw_s[wid];
    int*   sw = sn_s[wid];
    const int deg = counts[n], start = offsets[n];

    floatx4 sd4 = *(const floatx4*)(s1 + n * 16 + 8 + hg * 4);
    float lp[4] = {0.f, 0.f, 0.f, 0.f};
    float acc[4][4];
    #pragma unroll
    for (int h = 0; h < 4; h++)
        #pragma unroll
        for (int f = 0; f < 4; f++) acc[h][f] = 0.f;

    for (int e0 = 0; e0 < deg; e0 += CHK) {
        int ch = deg - e0; if (ch > CHK) ch = CHK;
        if (L < ch) {
            int sn = elist[start + e0 + L];
            sw[L] = sn;
            floatx4 ss4 = *(const floatx4*)(s1 + sn * 16 + hg * 4);
            floatx4 p4;
            #pragma unroll
            for (int h = 0; h < 4; h++) {
                float v = ss4[h] + sd4[h];
                v = (v > 0.f) ? v : 0.2f * v;
                float p = exp2f(v * LOG2E);
                p4[h] = p;
                lp[h] += p;
            }
            *(floatx4*)&pw[L * 4] = p4;
        }
        for (int e = 0; e < ch; e++) {
            floatx4 pv = *(const floatx4*)&pw[e * 4];
            ushort4 vv = *(const ushort4*)(hb + (size_t)sw[e] * 256 + 4 * L);
            float v0 = bf2f(vv.x), v1_ = bf2f(vv.y), v2 = bf2f(vv.z), v3 = bf2f(vv.w);
            #pragma unroll
            for (int h = 0; h < 4; h++) {
                acc[h][0] += pv[h] * v0;
                acc[h][1] += pv[h] * v1_;
                acc[h][2] += pv[h] * v2;
                acc[h][3] += pv[h] * v3;
            }
        }
    }
    #pragma unroll
    for (int off = 1; off < 64; off <<= 1)
        #pragma unroll
        for (int h = 0; h < 4; h++)
            lp[h] += __shfl_xor(lp[h], off, 64);
    #pragma unroll
    for (int h = 0; h < 4; h++) {
        float inv = 1.f / lp[h];
        short4 o = {f2bf(acc[h][0] * inv), f2bf(acc[h][1] * inv),
                    f2bf(acc[h][2] * inv), f2bf(acc[h][3] * inv)};
        *(short4*)(aggout + (size_t)n * 2048 + (hg * 4 + h) * 256 + 4 * L) = o;
    }
}

// ---------------- batchnorm stats (256 blocks -> low atomic contention) ----------------
__global__ __launch_bounds__(256) void bn_stats_kernel(const float* __restrict__ x, float* stats, int n) {
    int t = threadIdx.x;
    float s = 0.f, s2 = 0.f;
    for (int r = blockIdx.x; r < n; r += gridDim.x) {
        float v = x[(size_t)r * 256 + t];
        s += v; s2 += v * v;
    }
    atomicAdd(&stats[t], s);
    atomicAdd(&stats[256 + t], s2);
}

// ---------------- BN + ELU + bf16 write + layer-1 score, one block per node ----------------
__global__ __launch_bounds__(256) void bnapply_score1(
    const float* __restrict__ xg, const float* __restrict__ stats,
    const float* __restrict__ g, const float* __restrict__ be,
    const float* __restrict__ v1, short* __restrict__ hactb, float* __restrict__ s1)
{
    __shared__ float row[256];
    __shared__ float part[16][17];
    const int n = blockIdx.x, t = threadIdx.x;
    const float invN = 1.0f / NN;
    float mu = stats[t] * invN;
    float var = stats[256 + t] * invN - mu * mu;
    float v = g[t] * (xg[(size_t)n * 256 + t] - mu) * rsqrtf(var + 1e-5f) + be[t];
    v = (v > 0.f) ? v : (expf(v) - 1.f);   // ELU
    hactb[(size_t)n * 256 + t] = f2bf(v);
    row[t] = v;
    __syncthreads();
    int j = t & 15, f0 = t >> 4;
    float p = 0.f;
    #pragma unroll
    for (int k = 0; k < 16; k++)
        p += row[f0 * 16 + k] * v1[(f0 * 16 + k) * 16 + j];
    part[f0][j] = p;
    __syncthreads();
    if (t < 16) {
        float s = 0.f;
        #pragma unroll
        for (int k = 0; k < 16; k++) s += part[k][t];
        s1[n * 16 + t] = s;
    }
}

// ---------------- BN + ELU + residual (bf16) -> bf16, elementwise ----------------
__global__ __launch_bounds__(256) void bn_apply_kernel(
    const float* __restrict__ x, const float* __restrict__ stats,
    const float* __restrict__ g, const float* __restrict__ be,
    const unsigned short* __restrict__ resid, short* __restrict__ ybf, int total)
{
    int i = blockIdx.x * 256 + threadIdx.x;
    if (i >= total) return;
    int c = i & 255;
    const float invN = 1.0f / NN;
    float mu = stats[c] * invN;
    float var = stats[256 + c] * invN - mu * mu;
    float v = g[c] * (x[i] - mu) * rsqrtf(var + 1e-5f) + be[c];
    v = (v > 0.f) ? v : (expf(v) - 1.f);   // ELU
    v += bf2f(resid[i]);
    ybf[i] = f2bf(v);
}

// ---------------- launch ----------------
extern "C" void kernel_launch(void* const* d_in, const int* in_sizes, int n_in,
                              void* d_out, int out_size, void* d_ws, size_t ws_size,
                              hipStream_t stream) {
    const float* x      = (const float*)d_in[0];
    const int*   eidx   = (const int*)d_in[1];
    const float* W0     = (const float*)d_in[2];
    const float* a_src0 = (const float*)d_in[3];
    const float* a_dst0 = (const float*)d_in[4];
    const float* g0     = (const float*)d_in[6];
    const float* be0    = (const float*)d_in[7];
    const float* W1     = (const float*)d_in[8];
    const float* a_src1 = (const float*)d_in[9];
    const float* a_dst1 = (const float*)d_in[10];
    const float* g1     = (const float*)d_in[12];
    const float* be1    = (const float*)d_in[13];
    const float* Wc     = (const float*)d_in[14];
    const float* bc     = (const float*)d_in[15];
    float* out = (float*)d_out;

    const int E = in_sizes[1] / 2;
    const int* esrc = eidx;
    const int* edst = eidx + E;

    char* ws = (char*)d_ws;
    size_t off = 0;
    auto alloc = [&](size_t bytes) {
        void* p = ws + off;
        off += (bytes + 255) & ~(size_t)255;
        return p;
    };
    // stats + counts contiguous -> single memset
    float* stats   = (float*)alloc(1024 * 4);
    int*   counts  = (int*)alloc(NN * 4);
    float* out1    = (float*)alloc((size_t)NN * 256 * 4);
    short* h0b     = (short*)alloc((size_t)NN * 256 * 2);
    short* xb      = (short*)alloc((size_t)NN * 256 * 2);
    float* s0      = (float*)alloc((size_t)NN * 16 * 4);
    float* s1      = (float*)alloc((size_t)NN * 16 * 4);
    float* v1      = (float*)alloc(4096 * 4);
    float* h_gat0  = (float*)alloc((size_t)NN * 256 * 4);
    short* hactb   = (short*)alloc((size_t)NN * 256 * 2);
    short* agg1bf  = (short*)alloc((size_t)NN * 2048 * 2);
    short* W0T     = (short*)alloc((size_t)256 * 256 * 2);
    short* W1pT    = (short*)alloc((size_t)256 * 2048 * 2);
    short* WcT     = (short*)alloc((size_t)64 * 256 * 2);
    short* hfinbf  = (short*)alloc((size_t)NN * 256 * 2);
    int* offsets   = (int*)alloc((NN + 16) * 4);
    int* cursor    = (int*)alloc(NN * 4);
    int* elist     = (int*)alloc((size_t)(E + NN) * 4);

    float* stats0 = stats;
    float* stats1 = stats + 512;

    hipMemsetAsync(stats, 0, 1024 * 4 + NN * 4, stream);   // stats0+stats1+counts

    // prep + edge counting in one launch
    const int cntBlocks = (E + 255) / 256;
    prep_count<<<3324 + cntBlocks, 256, 0, stream>>>(
        x, W0, W1, a_src1, a_dst1, Wc, edst, E,
        xb, W0T, v1, W1pT, WcT, counts);

    scan_kernel<<<1, 1024, 0, stream>>>(counts, offsets, cursor, elist, NN);
    scatter_edges_kernel<<<cntBlocks, 256, 0, stream>>>(esrc, edst, cursor, elist, E);

    // layer 0 (BN=128 strip: xb read 2x instead of 4x)
    {
        dim3 grid(2, (NN + 63) / 64);
        gemm_bf16_w128<<<grid, 256, 0, stream>>>(xb, W0T, nullptr, h0b, nullptr,
                                                 NN, 256, 256, 1.0f);
    }
    score0_wave<<<NN / 4, 256, 0, stream>>>(
        (const unsigned short*)h0b, a_src0, a_dst0, s0);
    agg0_fused<<<NN / 4, 256, 0, stream>>>(
        (const unsigned short*)h0b, s0, offsets, counts, elist, h_gat0);
    bn_stats_kernel<<<256, 256, 0, stream>>>(h_gat0, stats0, NN);
    bnapply_score1<<<NN, 256, 0, stream>>>(h_gat0, stats0, g0, be0, v1, hactb, s1);

    // layer 1
    agg1_half<<<NN / 2, 256, 0, stream>>>(
        (const unsigned short*)hactb, s1, offsets, counts, elist, agg1bf);
    {
        dim3 grid(2, (NN + 63) / 64);
        gemm_bf16_w128<<<grid, 256, 0, stream>>>(agg1bf, W1pT, out1, nullptr, stats1,
                                                 NN, 256, 2048, 0.125f);
    }
    bn_apply_kernel<<<(NN * 256 + 255) / 256, 256, 0, stream>>>(
        out1, stats1, g1, be1, (const unsigned short*)hactb, hfinbf, NN * 256);

    // classifier (bf16 MFMA, BN=64)
    {
        dim3 grid(1, (NN + 63) / 64);
        gemm_bf16_v3<<<grid, 256, 0, stream>>>(hfinbf, WcT, out, bc,
                                               NN, NCLS, 256, 1.0f);
    }
}